// Round 3
// baseline (2720.672 us; speedup 1.0000x reference)
//
#include <hip/hip_runtime.h>
#include <cstdint>

#define NN 50000
#define EE 800000
#define GG 64

typedef unsigned short u16;
typedef __attribute__((ext_vector_type(8))) short bf16x8;
typedef __attribute__((ext_vector_type(4))) float f32x4;

__device__ __forceinline__ float bf2f(u16 v) { return __uint_as_float(((unsigned)v) << 16); }
__device__ __forceinline__ u16 f2bf(float f) {
  unsigned u = __float_as_uint(f);
  return (u16)((u + 0x7fffu + ((u >> 16) & 1u)) >> 16);
}

__device__ __forceinline__ void gload_lds16(const void* g, void* l) {
  __builtin_amdgcn_global_load_lds(
      (const __attribute__((address_space(1))) void*)g,
      (__attribute__((address_space(3))) void*)l,
      16, 0, 0);
}

__global__ void k_sentinel(float* out) { out[threadIdx.x] = 1e12f; }

// ---------------- encoder: hb = bf16(relu(x @ enc_W + b)) --------------------
__global__ __launch_bounds__(256) void k_encoder(
    const float* __restrict__ x, const float* __restrict__ W,
    const float* __restrict__ b, u16* __restrict__ hb) {
  int idx = blockIdx.x * 256 + threadIdx.x;
  if (idx >= NN * 256) return;
  int row = idx >> 8, j = idx & 255;
  float s = b[j];
#pragma unroll
  for (int k = 0; k < 6; ++k) s += x[row * 6 + k] * W[k * 256 + j];
  hb[idx] = f2bf(fmaxf(s, 0.f));
}

// ---------------- graph size features (no hot atomics) -----------------------
// out-degree histogram: 800k adds over 50k addresses (avg 16-way) — cheap.
__global__ __launch_bounds__(256) void k_outdeg(const int* __restrict__ src,
                                                int* __restrict__ outdeg) {
  int i = blockIdx.x * 256 + threadIdx.x;
  if (i < EE) atomicAdd(&outdeg[src[i]], 1);
}

// one block per graph: binary-search boundaries in sorted batch, reduce outdeg.
__global__ __launch_bounds__(256) void k_graph_feats(const int* __restrict__ batch,
                                                     const int* __restrict__ outdeg,
                                                     float* __restrict__ gf) {
  __shared__ int red[256];
  int g = blockIdx.x, tid = threadIdx.x;
  auto lb = [&](int v) {
    int lo = 0, hi = NN;
    while (lo < hi) { int m = (lo + hi) >> 1; if (batch[m] < v) lo = m + 1; else hi = m; }
    return lo;
  };
  int bs = lb(g), be = lb(g + 1);
  int s = 0;
  for (int i = bs + tid; i < be; i += 256) s += outdeg[i];
  red[tid] = s;
  __syncthreads();
  for (int off = 128; off > 0; off >>= 1) {
    if (tid < off) red[tid] += red[tid + off];
    __syncthreads();
  }
  if (tid == 0) {
    gf[g * 2] = logf((float)(be - bs) + 1.f);
    gf[g * 2 + 1] = logf((float)red[0] + 1.f);
  }
}

// ---------------- router (fp32 end-to-end, 8 nodes/block) --------------------
__global__ __launch_bounds__(256) void k_router(
    const float* __restrict__ x, const float* __restrict__ encW, const float* __restrict__ encb,
    const int* __restrict__ batch, const float* __restrict__ gf,
    const float* __restrict__ W1, const float* __restrict__ b1,
    const float* __restrict__ W2, const float* __restrict__ b2,
    float* __restrict__ sparse) {
  __shared__ float hs[8][256];
  __shared__ float rs[8][256];
  __shared__ float xv[8][6];
  __shared__ float sf[8][2];
  __shared__ float lg[8][8];
  int tid = threadIdx.x;
  int nb = blockIdx.x * 8;
  if (tid < 48) {
    int r = tid / 6, k = tid % 6;
    int node = nb + r;
    xv[r][k] = (node < NN) ? x[node * 6 + k] : 0.f;
  }
  if (tid >= 48 && tid < 56) {
    int r = tid - 48;
    int node = nb + r;
    int g = (node < NN) ? batch[node] : 0;
    sf[r][0] = gf[g * 2];
    sf[r][1] = gf[g * 2 + 1];
  }
  __syncthreads();
  {
    float wcol[6];
#pragma unroll
    for (int k = 0; k < 6; ++k) wcol[k] = encW[k * 256 + tid];
    float bb = encb[tid];
#pragma unroll
    for (int r = 0; r < 8; ++r) {
      float s = bb;
#pragma unroll
      for (int k = 0; k < 6; ++k) s += xv[r][k] * wcol[k];
      hs[r][tid] = fmaxf(s, 0.f);
    }
  }
  __syncthreads();
  float acc[8];
  float bb = b1[tid];
#pragma unroll
  for (int r = 0; r < 8; ++r) acc[r] = bb;
  for (int k = 0; k < 256; ++k) {
    float w = W1[k * 256 + tid];
#pragma unroll
    for (int r = 0; r < 8; ++r) acc[r] += hs[r][k] * w;
  }
  {
    float w0 = W1[256 * 256 + tid], w1v = W1[257 * 256 + tid];
#pragma unroll
    for (int r = 0; r < 8; ++r) acc[r] += sf[r][0] * w0 + sf[r][1] * w1v;
  }
#pragma unroll
  for (int r = 0; r < 8; ++r) rs[r][tid] = fmaxf(acc[r], 0.f);
  __syncthreads();
  if (tid < 64) {
    int r = tid >> 3, e = tid & 7;
    float s = b2[e];
    for (int k = 0; k < 256; ++k) s += rs[r][k] * W2[k * 8 + e];
    lg[r][e] = s;
  }
  __syncthreads();
  if (tid < 8) {
    int node = nb + tid;
    if (node < NN) {
      float v1 = lg[tid][0];
      int j1 = 0;
#pragma unroll
      for (int j = 1; j < 8; ++j) {
        float v = lg[tid][j];
        if (v > v1) { v1 = v; j1 = j; }
      }
      float v2 = -1e30f;
      int j2 = 0;
#pragma unroll
      for (int j = 0; j < 8; ++j) {
        if (j == j1) continue;
        float v = lg[tid][j];
        if (v > v2) { v2 = v; j2 = j; }
      }
      float ex = expf(v2 - v1);
      float wa = 1.f / (1.f + ex), wb = ex / (1.f + ex);
      float* sp = sparse + node * 8;
#pragma unroll
      for (int j = 0; j < 8; ++j) sp[j] = 0.f;
      sp[j1] = wa;
      sp[j2] = wb;
    }
  }
}

// ---------------- CSR build (by dst) -----------------------------------------
__global__ __launch_bounds__(256) void k_deg(const int* __restrict__ dst, int* __restrict__ deg) {
  int i = blockIdx.x * 256 + threadIdx.x;
  if (i < EE) atomicAdd(&deg[dst[i]], 1);
}

__global__ __launch_bounds__(1024) void k_scan(const int* __restrict__ deg,
                                               int* __restrict__ rowptr) {
  __shared__ int tmp[1024];
  __shared__ int carry;
  if (threadIdx.x == 0) { carry = 0; rowptr[0] = 0; }
  __syncthreads();
  for (int base = 0; base < NN; base += 1024) {
    int i = base + threadIdx.x;
    int v = (i < NN) ? deg[i] : 0;
    tmp[threadIdx.x] = v;
    __syncthreads();
    for (int off = 1; off < 1024; off <<= 1) {
      int t = (threadIdx.x >= off) ? tmp[threadIdx.x - off] : 0;
      __syncthreads();
      tmp[threadIdx.x] += t;
      __syncthreads();
    }
    if (i < NN) rowptr[i + 1] = carry + tmp[threadIdx.x];
    int last = tmp[1023];
    __syncthreads();
    if (threadIdx.x == 0) carry += last;
    __syncthreads();
  }
}

__global__ __launch_bounds__(256) void k_fill(const int* __restrict__ ei,
                                              const int* __restrict__ rowptr,
                                              int* __restrict__ cursor, int* __restrict__ csrc) {
  int i = blockIdx.x * 256 + threadIdx.x;
  if (i < EE) {
    int s = ei[i], d = ei[EE + i];
    int pos = atomicAdd(&cursor[d], 1);
    csrc[rowptr[d] + pos] = s;
  }
}

// ---------------- SpMM: Y[d] = sum_{e: dst=d} X[src[e]]  (bf16 in/out) -------
__global__ __launch_bounds__(256) void k_spmm256(
    const int* __restrict__ rowptr, const int* __restrict__ csrc,
    const u16* __restrict__ X, u16* __restrict__ Y) {
  int wave = threadIdx.x >> 6, lane = threadIdx.x & 63;
  int d = blockIdx.x * 4 + wave;
  if (d >= NN) return;
  int s0 = rowptr[d], s1 = rowptr[d + 1];
  int c4 = lane * 4;
  float a0 = 0.f, a1 = 0.f, a2 = 0.f, a3 = 0.f;
  int i = s0;
  for (; i + 2 <= s1; i += 2) {
    int sa = csrc[i], sb = csrc[i + 1];
    ushort4 va = *(const ushort4*)(X + sa * 256 + c4);
    ushort4 vb = *(const ushort4*)(X + sb * 256 + c4);
    a0 += bf2f(va.x) + bf2f(vb.x);
    a1 += bf2f(va.y) + bf2f(vb.y);
    a2 += bf2f(va.z) + bf2f(vb.z);
    a3 += bf2f(va.w) + bf2f(vb.w);
  }
  if (i < s1) {
    int sa = csrc[i];
    ushort4 va = *(const ushort4*)(X + sa * 256 + c4);
    a0 += bf2f(va.x);
    a1 += bf2f(va.y);
    a2 += bf2f(va.z);
    a3 += bf2f(va.w);
  }
  ushort4 o;
  o.x = f2bf(a0); o.y = f2bf(a1); o.z = f2bf(a2); o.w = f2bf(a3);
  *(ushort4*)(Y + d * 256 + c4) = o;
}

// ---------------- weight transpose+bf16: W[m][k][j] -> Wt[m][j][k] -----------
__global__ __launch_bounds__(256) void k_transpose(const float* __restrict__ W,
                                                   u16* __restrict__ Wt, int nmat) {
  int idx = blockIdx.x * 256 + threadIdx.x;
  if (idx >= nmat * 65536) return;
  int m = idx >> 16, rem = idx & 65535;
  int k = rem >> 8, j = rem & 255;
  Wt[(m << 16) + (j << 8) + k] = f2bf(W[idx]);
}

// ---------------- fused dual-source MFMA GEMM v2 -----------------------------
// Y[m,0:256] = act( X1[m,:]@W1t^T + X2[m,:]@W2t^T + bias )
// 128x256 tile, 8 waves (64x64), BK=32, dbuf LDS, stage-early + counted vmcnt,
// XOR-swizzled LDS (swizzle on global SOURCE, linear gload_lds dest, rule #21).
__global__ __launch_bounds__(512) void k_gemm(
    const u16* __restrict__ X1, const u16* __restrict__ X2,
    const u16* __restrict__ W1t, const u16* __restrict__ W2t,
    const float* __restrict__ bias, u16* __restrict__ Y, int relu) {
  __shared__ __align__(16) u16 Alds[2][128 * 32];  // 2 x 8KB
  __shared__ __align__(16) u16 Blds[2][256 * 32];  // 2 x 16KB
  int tid = threadIdx.x;
  int wave = tid >> 6, lane = tid & 63;
  int l15 = lane & 15, l4 = lane >> 4;
  int m0 = blockIdx.x * 128;
  int wr = wave >> 2, wc = wave & 3;
  const f32x4 fz = {0.f, 0.f, 0.f, 0.f};
  f32x4 acc[4][4];
#pragma unroll
  for (int a = 0; a < 4; ++a)
#pragma unroll
    for (int b = 0; b < 4; ++b) acc[a][b] = fz;

  auto stage = [&](int t) {
    const u16* xs = (t < 8) ? X1 : X2;
    const u16* wsrc = (t < 8) ? W1t : W2t;
    int kb = (t & 7) * 32;
    int half = t & 1;
    {
      int flat = wave * 1024 + lane * 16;  // 8KB total = 512thr x 16B
      int row = flat >> 6, colb = flat & 63;
      int scol = colb ^ (((row >> 1) & 3) << 4);  // inverse-swizzle the SOURCE
      int gr = m0 + row;
      if (gr > NN - 1) gr = NN - 1;  // clamp; masked on write; row stays in-block
      gload_lds16(xs + gr * 256 + kb + (scol >> 1), (char*)Alds[half] + flat);
    }
#pragma unroll
    for (int q = 0; q < 2; ++q) {
      int flat = q * 8192 + wave * 1024 + lane * 16;
      int row = flat >> 6, colb = flat & 63;
      int scol = colb ^ (((row >> 1) & 3) << 4);
      gload_lds16(wsrc + row * 256 + kb + (scol >> 1), (char*)Blds[half] + flat);
    }
  };

  stage(0);
  for (int kt = 0; kt < 16; ++kt) {
    if (kt < 15) {
      stage(kt + 1);  // 3 loads in flight across the whole compute phase
      asm volatile("s_waitcnt vmcnt(3)" ::: "memory");  // tile-kt loads landed
    } else {
      asm volatile("s_waitcnt vmcnt(0)" ::: "memory");
    }
    __builtin_amdgcn_sched_barrier(0);
    __builtin_amdgcn_s_barrier();  // tile-kt visible to all waves
    __builtin_amdgcn_sched_barrier(0);
    const char* Ab = (const char*)Alds[kt & 1];
    const char* Bb = (const char*)Blds[kt & 1];
    bf16x8 af[4], bfv[4];
#pragma unroll
    for (int mi = 0; mi < 4; ++mi) {
      int r = wr * 64 + mi * 16 + l15;
      af[mi] = *(const bf16x8*)(Ab + r * 64 + ((l4 * 16) ^ (((r >> 1) & 3) << 4)));
    }
#pragma unroll
    for (int nj = 0; nj < 4; ++nj) {
      int c = wc * 64 + nj * 16 + l15;
      bfv[nj] = *(const bf16x8*)(Bb + c * 64 + ((l4 * 16) ^ (((c >> 1) & 3) << 4)));
    }
#pragma unroll
    for (int mi = 0; mi < 4; ++mi)
#pragma unroll
      for (int nj = 0; nj < 4; ++nj)
        acc[mi][nj] =
            __builtin_amdgcn_mfma_f32_16x16x32_bf16(af[mi], bfv[nj], acc[mi][nj], 0, 0, 0);
    __builtin_amdgcn_sched_barrier(0);
    __builtin_amdgcn_s_barrier();  // all reads of buf[kt&1] done before overwrite
  }
  // epilogue: C/D map col=lane&15, row=(lane>>4)*4+reg  [m89-verified]
#pragma unroll
  for (int mi = 0; mi < 4; ++mi) {
    int rbase = m0 + wr * 64 + mi * 16 + l4 * 4;
#pragma unroll
    for (int nj = 0; nj < 4; ++nj) {
      int col = wc * 64 + nj * 16 + l15;
      float bv = bias[col];
#pragma unroll
      for (int r2 = 0; r2 < 4; ++r2) {
        int row = rbase + r2;
        if (row < NN) {
          float v = acc[mi][nj][r2] + bv;
          if (relu) v = fmaxf(v, 0.f);
          Y[row * 256 + col] = f2bf(v);
        }
      }
    }
  }
}

// ---------------- output projection: Y4[n] = [he@Wr (2), he@Wn (2)] ----------
__global__ __launch_bounds__(256) void k_outproj(
    const u16* __restrict__ he, const float* __restrict__ Wr,
    const float* __restrict__ Wn, float* __restrict__ Y4) {
  __shared__ float Ws[256 * 4];
  int tid = threadIdx.x;
  Ws[tid * 4 + 0] = Wr[tid * 2];
  Ws[tid * 4 + 1] = Wr[tid * 2 + 1];
  Ws[tid * 4 + 2] = Wn[tid * 2];
  Ws[tid * 4 + 3] = Wn[tid * 2 + 1];
  __syncthreads();
  int wave = tid >> 6, lane = tid & 63;
  int node = blockIdx.x * 4 + wave;
  if (node >= NN) return;
  const u16* hrow = he + node * 256;
  int k0 = lane * 4;
  ushort4 hv4 = *(const ushort4*)(hrow + k0);
  float hv[4] = {bf2f(hv4.x), bf2f(hv4.y), bf2f(hv4.z), bf2f(hv4.w)};
  float a0 = 0.f, a1 = 0.f, a2 = 0.f, a3 = 0.f;
#pragma unroll
  for (int t = 0; t < 4; ++t) {
    float hvv = hv[t];
    const float* w = Ws + (k0 + t) * 4;
    a0 += hvv * w[0];
    a1 += hvv * w[1];
    a2 += hvv * w[2];
    a3 += hvv * w[3];
  }
#pragma unroll
  for (int off = 32; off > 0; off >>= 1) {
    a0 += __shfl_down(a0, off);
    a1 += __shfl_down(a1, off);
    a2 += __shfl_down(a2, off);
    a3 += __shfl_down(a3, off);
  }
  if (lane == 0) {
    float* y = Y4 + node * 4;
    y[0] = a0; y[1] = a1; y[2] = a2; y[3] = a3;
  }
}

// out[d] += sparse[d,e] * (Y4[d,0:2] + sum_in-edges Y4[src,2:4] + b)
__global__ __launch_bounds__(256) void k_out_combine(
    const int* __restrict__ rowptr, const int* __restrict__ csrc,
    const float* __restrict__ Y4, const float* __restrict__ sparse,
    const float* __restrict__ ob, float* __restrict__ out, int e) {
  int d = blockIdx.x * 256 + threadIdx.x;
  if (d >= NN) return;
  float a0 = 0.f, a1 = 0.f;
  for (int i = rowptr[d]; i < rowptr[d + 1]; ++i) {
    int s = csrc[i];
    a0 += Y4[s * 4 + 2];
    a1 += Y4[s * 4 + 3];
  }
  float w = sparse[d * 8 + e];
  out[d * 2] += w * (Y4[d * 4] + a0 + ob[0]);
  out[d * 2 + 1] += w * (Y4[d * 4 + 1] + a1 + ob[1]);
}

extern "C" void kernel_launch(void* const* d_in, const int* in_sizes, int n_in,
                              void* d_out, int out_size, void* d_ws, size_t ws_size,
                              hipStream_t stream) {
  const float* x = (const float*)d_in[0];
  const int* ei = (const int*)d_in[1];
  const int* batch = (const int*)d_in[2];
  const float* enc_W = (const float*)d_in[3];
  const float* enc_b = (const float*)d_in[4];
  const float* rW1 = (const float*)d_in[5];
  const float* rb1 = (const float*)d_in[6];
  const float* rW2 = (const float*)d_in[7];
  const float* rb2 = (const float*)d_in[8];
  const float* hid_Wr = (const float*)d_in[9];
  const float* hid_Wn = (const float*)d_in[10];
  const float* hid_b = (const float*)d_in[11];
  const float* out_Wr = (const float*)d_in[12];
  const float* out_Wn = (const float*)d_in[13];
  const float* out_b = (const float*)d_in[14];
  float* out = (float*)d_out;

  char* ws = (char*)d_ws;
  size_t off = 0;
  auto alloc = [&](size_t bytes) -> void* {
    void* p = ws + off;
    off = (off + bytes + 511) & ~(size_t)511;
    return p;
  };
  u16* hb = (u16*)alloc((size_t)NN * 256 * 2);     // 25.6 MB
  u16* agg0 = (u16*)alloc((size_t)NN * 256 * 2);   // 25.6 MB
  u16* he = (u16*)alloc((size_t)NN * 256 * 2);     // 25.6 MB
  u16* agg = (u16*)alloc((size_t)NN * 256 * 2);    // 25.6 MB
  u16* WrT = (u16*)alloc((size_t)24 * 65536 * 2);  // 3.15 MB
  u16* WnT = (u16*)alloc((size_t)24 * 65536 * 2);  // 3.15 MB
  int* deg = (int*)alloc((size_t)NN * 4);
  int* rowptr = (int*)alloc((size_t)(NN + 1) * 4);
  int* cursor = (int*)alloc((size_t)NN * 4);
  int* outdeg = (int*)alloc((size_t)NN * 4);
  int* csrc = (int*)alloc((size_t)EE * 4);  // 3.2 MB
  float* gf = (float*)alloc(GG * 2 * 4);
  float* sparse = (float*)alloc((size_t)NN * 8 * 4);  // 1.6 MB
  float* Y4 = (float*)alloc((size_t)NN * 4 * 4);      // 0.8 MB
  if (off > ws_size) {  // workspace too small -> unambiguous sentinel, no OOB
    k_sentinel<<<1, 2, 0, stream>>>(out);
    return;
  }

  hipMemsetAsync(deg, 0, (size_t)NN * 4, stream);
  hipMemsetAsync(cursor, 0, (size_t)NN * 4, stream);
  hipMemsetAsync(outdeg, 0, (size_t)NN * 4, stream);
  hipMemsetAsync(out, 0, (size_t)NN * 2 * 4, stream);

  k_encoder<<<(NN * 256 + 255) / 256, 256, 0, stream>>>(x, enc_W, enc_b, hb);
  k_transpose<<<(24 * 65536 + 255) / 256, 256, 0, stream>>>(hid_Wr, WrT, 24);
  k_transpose<<<(24 * 65536 + 255) / 256, 256, 0, stream>>>(hid_Wn, WnT, 24);
  k_outdeg<<<(EE + 255) / 256, 256, 0, stream>>>(ei, outdeg);
  k_graph_feats<<<GG, 256, 0, stream>>>(batch, outdeg, gf);
  k_router<<<NN / 8, 256, 0, stream>>>(x, enc_W, enc_b, batch, gf, rW1, rb1, rW2, rb2, sparse);
  k_deg<<<(EE + 255) / 256, 256, 0, stream>>>(ei + EE, deg);
  k_scan<<<1, 1024, 0, stream>>>(deg, rowptr);
  k_fill<<<(EE + 255) / 256, 256, 0, stream>>>(ei, rowptr, cursor, csrc);

  const int gemm_grid = (NN + 127) / 128;
  // shared layer-0 aggregation of h (identical input for every expert)
  k_spmm256<<<(NN + 3) / 4, 256, 0, stream>>>(rowptr, csrc, hb, agg0);
  for (int e = 0; e < 8; ++e) {
    k_gemm<<<gemm_grid, 512, 0, stream>>>(hb, agg0, WrT + e * 65536, WnT + e * 65536,
                                          hid_b + e * 256, he, 1);
    for (int l = 1; l < 3; ++l) {
      k_spmm256<<<(NN + 3) / 4, 256, 0, stream>>>(rowptr, csrc, he, agg);
      k_gemm<<<gemm_grid, 512, 0, stream>>>(he, agg, WrT + (l * 8 + e) * 65536,
                                            WnT + (l * 8 + e) * 65536,
                                            hid_b + (l * 8 + e) * 256, he, 1);
    }
    // output layer: project first (H->4), aggregate the tiny vectors (linearity)
    k_outproj<<<(NN + 3) / 4, 256, 0, stream>>>(he, out_Wr + e * 512, out_Wn + e * 512, Y4);
    k_out_combine<<<(NN + 255) / 256, 256, 0, stream>>>(rowptr, csrc, Y4, sparse,
                                                        out_b + e * 2, out, e);
  }
}

// Round 4
// 2518.904 us; speedup vs baseline: 1.0801x; 1.0801x over previous
//
#include <hip/hip_runtime.h>
#include <cstdint>

#define NN 50000
#define EE 800000
#define GG 64

typedef unsigned short u16;
typedef __attribute__((ext_vector_type(8))) short bf16x8;
typedef __attribute__((ext_vector_type(4))) float f32x4;

__device__ __forceinline__ float bf2f(u16 v) { return __uint_as_float(((unsigned)v) << 16); }
__device__ __forceinline__ u16 f2bf(float f) {
  unsigned u = __float_as_uint(f);
  return (u16)((u + 0x7fffu + ((u >> 16) & 1u)) >> 16);
}

__device__ __forceinline__ void gload_lds16(const void* g, void* l) {
  __builtin_amdgcn_global_load_lds(
      (const __attribute__((address_space(1))) void*)g,
      (__attribute__((address_space(3))) void*)l,
      16, 0, 0);
}

__global__ void k_sentinel(float* out) { out[threadIdx.x] = 1e12f; }

// ---------------- encoder: hb = bf16(relu(x @ enc_W + b)) --------------------
__global__ __launch_bounds__(256) void k_encoder(
    const float* __restrict__ x, const float* __restrict__ W,
    const float* __restrict__ b, u16* __restrict__ hb) {
  int idx = blockIdx.x * 256 + threadIdx.x;
  if (idx >= NN * 256) return;
  int row = idx >> 8, j = idx & 255;
  float s = b[j];
#pragma unroll
  for (int k = 0; k < 6; ++k) s += x[row * 6 + k] * W[k * 256 + j];
  hb[idx] = f2bf(fmaxf(s, 0.f));
}

// ---------------- graph size features (no hot atomics) -----------------------
__global__ __launch_bounds__(256) void k_outdeg(const int* __restrict__ src,
                                                int* __restrict__ outdeg) {
  int i = blockIdx.x * 256 + threadIdx.x;
  if (i < EE) atomicAdd(&outdeg[src[i]], 1);
}

__global__ __launch_bounds__(256) void k_graph_feats(const int* __restrict__ batch,
                                                     const int* __restrict__ outdeg,
                                                     float* __restrict__ gf) {
  __shared__ int red[256];
  int g = blockIdx.x, tid = threadIdx.x;
  auto lb = [&](int v) {
    int lo = 0, hi = NN;
    while (lo < hi) { int m = (lo + hi) >> 1; if (batch[m] < v) lo = m + 1; else hi = m; }
    return lo;
  };
  int bs = lb(g), be = lb(g + 1);
  int s = 0;
  for (int i = bs + tid; i < be; i += 256) s += outdeg[i];
  red[tid] = s;
  __syncthreads();
  for (int off = 128; off > 0; off >>= 1) {
    if (tid < off) red[tid] += red[tid + off];
    __syncthreads();
  }
  if (tid == 0) {
    gf[g * 2] = logf((float)(be - bs) + 1.f);
    gf[g * 2 + 1] = logf((float)red[0] + 1.f);
  }
}

// ---------------- router (fp32, transposed LDS: broadcast b128 reads) --------
__global__ __launch_bounds__(256) void k_router(
    const float* __restrict__ x, const float* __restrict__ encW, const float* __restrict__ encb,
    const int* __restrict__ batch, const float* __restrict__ gf,
    const float* __restrict__ W1, const float* __restrict__ b1,
    const float* __restrict__ W2, const float* __restrict__ b2,
    float* __restrict__ sparse) {
  __shared__ __align__(16) float hs_t[258][8];  // k-major: row k holds h[0..7][k]
  __shared__ __align__(16) float rs_t[256][8];
  __shared__ float xv[8][6];
  __shared__ float sf[8][2];
  __shared__ float lg[8][8];
  int tid = threadIdx.x;
  int nb = blockIdx.x * 8;
  if (tid < 48) {
    int r = tid / 6, k = tid % 6;
    int node = nb + r;
    xv[r][k] = (node < NN) ? x[node * 6 + k] : 0.f;
  }
  if (tid >= 48 && tid < 56) {
    int r = tid - 48;
    int node = nb + r;
    int g = (node < NN) ? batch[node] : 0;
    sf[r][0] = gf[g * 2];
    sf[r][1] = gf[g * 2 + 1];
  }
  __syncthreads();
  {
    float wcol[6];
#pragma unroll
    for (int k = 0; k < 6; ++k) wcol[k] = encW[k * 256 + tid];
    float bb = encb[tid];
#pragma unroll
    for (int r = 0; r < 8; ++r) {
      float s = bb;
#pragma unroll
      for (int k = 0; k < 6; ++k) s += xv[r][k] * wcol[k];
      hs_t[tid][r] = fmaxf(s, 0.f);  // one-time write; conflicts negligible
    }
  }
  if (tid < 16) {  // rows 256,257 = size feats
    int r = tid >> 1, c = tid & 1;
    hs_t[256 + c][r] = sf[r][c];
  }
  __syncthreads();
  float acc[8];
  {
    float bb = b1[tid];
#pragma unroll
    for (int r = 0; r < 8; ++r) acc[r] = bb;
  }
  for (int k = 0; k < 258; ++k) {
    float w = W1[k * 256 + tid];
    float4 ha = *(const float4*)&hs_t[k][0];  // wave-uniform addr -> broadcast
    float4 hb4 = *(const float4*)&hs_t[k][4];
    acc[0] += ha.x * w; acc[1] += ha.y * w; acc[2] += ha.z * w; acc[3] += ha.w * w;
    acc[4] += hb4.x * w; acc[5] += hb4.y * w; acc[6] += hb4.z * w; acc[7] += hb4.w * w;
  }
#pragma unroll
  for (int r = 0; r < 8; ++r) rs_t[tid][r] = fmaxf(acc[r], 0.f);
  __syncthreads();
  if (tid < 64) {
    int r = tid >> 3, e = tid & 7;
    float s = b2[e];
    for (int k = 0; k < 256; ++k) s += rs_t[k][r] * W2[k * 8 + e];  // 8 addrs, 8 banks
    lg[r][e] = s;
  }
  __syncthreads();
  if (tid < 8) {
    int node = nb + tid;
    if (node < NN) {
      float v1 = lg[tid][0];
      int j1 = 0;
#pragma unroll
      for (int j = 1; j < 8; ++j) {
        float v = lg[tid][j];
        if (v > v1) { v1 = v; j1 = j; }
      }
      float v2 = -1e30f;
      int j2 = 0;
#pragma unroll
      for (int j = 0; j < 8; ++j) {
        if (j == j1) continue;
        float v = lg[tid][j];
        if (v > v2) { v2 = v; j2 = j; }
      }
      float ex = expf(v2 - v1);
      float wa = 1.f / (1.f + ex), wb = ex / (1.f + ex);
      float* sp = sparse + node * 8;
#pragma unroll
      for (int j = 0; j < 8; ++j) sp[j] = 0.f;
      sp[j1] = wa;
      sp[j2] = wb;
    }
  }
}

// ---------------- CSR build (by dst) -----------------------------------------
__global__ __launch_bounds__(256) void k_deg(const int* __restrict__ dst, int* __restrict__ deg) {
  int i = blockIdx.x * 256 + threadIdx.x;
  if (i < EE) atomicAdd(&deg[dst[i]], 1);
}

__global__ __launch_bounds__(1024) void k_scan(const int* __restrict__ deg,
                                               int* __restrict__ rowptr) {
  __shared__ int tmp[1024];
  __shared__ int carry;
  if (threadIdx.x == 0) { carry = 0; rowptr[0] = 0; }
  __syncthreads();
  for (int base = 0; base < NN; base += 1024) {
    int i = base + threadIdx.x;
    int v = (i < NN) ? deg[i] : 0;
    tmp[threadIdx.x] = v;
    __syncthreads();
    for (int off = 1; off < 1024; off <<= 1) {
      int t = (threadIdx.x >= off) ? tmp[threadIdx.x - off] : 0;
      __syncthreads();
      tmp[threadIdx.x] += t;
      __syncthreads();
    }
    if (i < NN) rowptr[i + 1] = carry + tmp[threadIdx.x];
    int last = tmp[1023];
    __syncthreads();
    if (threadIdx.x == 0) carry += last;
    __syncthreads();
  }
}

__global__ __launch_bounds__(256) void k_fill(const int* __restrict__ ei,
                                              const int* __restrict__ rowptr,
                                              int* __restrict__ cursor, int* __restrict__ csrc) {
  int i = blockIdx.x * 256 + threadIdx.x;
  if (i < EE) {
    int s = ei[i], d = ei[EE + i];
    int pos = atomicAdd(&cursor[d], 1);
    csrc[rowptr[d] + pos] = s;
  }
}

// ---------------- SpMM (expert-batched): Y[g][d] = sum X[g][src[e]] ----------
__global__ __launch_bounds__(256) void k_spmm256(
    const int* __restrict__ rowptr, const int* __restrict__ csrc,
    const u16* __restrict__ Xb, size_t xs, u16* __restrict__ Yb, size_t ys) {
  const u16* X = Xb + (size_t)blockIdx.y * xs;
  u16* Y = Yb + (size_t)blockIdx.y * ys;
  int wave = threadIdx.x >> 6, lane = threadIdx.x & 63;
  int d = blockIdx.x * 4 + wave;
  if (d >= NN) return;
  int s0 = rowptr[d], s1 = rowptr[d + 1];
  int c4 = lane * 4;
  float a0 = 0.f, a1 = 0.f, a2 = 0.f, a3 = 0.f;
  int i = s0;
  for (; i + 2 <= s1; i += 2) {
    int sa = csrc[i], sb = csrc[i + 1];
    ushort4 va = *(const ushort4*)(X + sa * 256 + c4);
    ushort4 vb = *(const ushort4*)(X + sb * 256 + c4);
    a0 += bf2f(va.x) + bf2f(vb.x);
    a1 += bf2f(va.y) + bf2f(vb.y);
    a2 += bf2f(va.z) + bf2f(vb.z);
    a3 += bf2f(va.w) + bf2f(vb.w);
  }
  if (i < s1) {
    int sa = csrc[i];
    ushort4 va = *(const ushort4*)(X + sa * 256 + c4);
    a0 += bf2f(va.x);
    a1 += bf2f(va.y);
    a2 += bf2f(va.z);
    a3 += bf2f(va.w);
  }
  ushort4 o;
  o.x = f2bf(a0); o.y = f2bf(a1); o.z = f2bf(a2); o.w = f2bf(a3);
  *(ushort4*)(Y + d * 256 + c4) = o;
}

// ---------------- weight transpose+bf16: W[m][k][j] -> Wt[m][j][k] -----------
__global__ __launch_bounds__(256) void k_transpose(const float* __restrict__ W,
                                                   u16* __restrict__ Wt, int nmat) {
  int idx = blockIdx.x * 256 + threadIdx.x;
  if (idx >= nmat * 65536) return;
  int m = idx >> 16, rem = idx & 65535;
  int k = rem >> 8, j = rem & 255;
  Wt[(m << 16) + (j << 8) + k] = f2bf(W[idx]);
}

// ---------------- fused dual-source MFMA GEMM (expert-batched) ---------------
// Y[g][m,0:256] = act( X1[g][m,:]@W1t[g]^T + X2[g][m,:]@W2t[g]^T + bias[g] )
// 128x256 tile, 8 waves (64x64), BK=32, dbuf LDS, stage-early + counted vmcnt,
// XOR-swizzled LDS (swizzle on global SOURCE, linear gload_lds dest).
__global__ __launch_bounds__(512) void k_gemm(
    const u16* __restrict__ X1b, size_t x1s, const u16* __restrict__ X2b, size_t x2s,
    const u16* __restrict__ W1tb, const u16* __restrict__ W2tb, size_t wst,
    const float* __restrict__ biasb, size_t bst,
    u16* __restrict__ Yb, size_t yst, int relu) {
  __shared__ __align__(16) u16 Alds[2][128 * 32];  // 2 x 8KB
  __shared__ __align__(16) u16 Blds[2][256 * 32];  // 2 x 16KB
  int g = blockIdx.y;
  const u16* X1 = X1b + (size_t)g * x1s;
  const u16* X2 = X2b + (size_t)g * x2s;
  const u16* W1t = W1tb + (size_t)g * wst;
  const u16* W2t = W2tb + (size_t)g * wst;
  const float* bias = biasb + (size_t)g * bst;
  u16* Y = Yb + (size_t)g * yst;
  int tid = threadIdx.x;
  int wave = tid >> 6, lane = tid & 63;
  int l15 = lane & 15, l4 = lane >> 4;
  int m0 = blockIdx.x * 128;
  int wr = wave >> 2, wc = wave & 3;
  const f32x4 fz = {0.f, 0.f, 0.f, 0.f};
  f32x4 acc[4][4];
#pragma unroll
  for (int a = 0; a < 4; ++a)
#pragma unroll
    for (int b = 0; b < 4; ++b) acc[a][b] = fz;

  auto stage = [&](int t) {
    const u16* xs = (t < 8) ? X1 : X2;
    const u16* wsrc = (t < 8) ? W1t : W2t;
    int kb = (t & 7) * 32;
    int half = t & 1;
    {
      int flat = wave * 1024 + lane * 16;
      int row = flat >> 6, colb = flat & 63;
      int scol = colb ^ (((row >> 1) & 3) << 4);  // inverse-swizzle the SOURCE
      int gr = m0 + row;
      if (gr > NN - 1) gr = NN - 1;
      gload_lds16(xs + gr * 256 + kb + (scol >> 1), (char*)Alds[half] + flat);
    }
#pragma unroll
    for (int q = 0; q < 2; ++q) {
      int flat = q * 8192 + wave * 1024 + lane * 16;
      int row = flat >> 6, colb = flat & 63;
      int scol = colb ^ (((row >> 1) & 3) << 4);
      gload_lds16(wsrc + row * 256 + kb + (scol >> 1), (char*)Blds[half] + flat);
    }
  };

  stage(0);
  for (int kt = 0; kt < 16; ++kt) {
    if (kt < 15) {
      stage(kt + 1);
      asm volatile("s_waitcnt vmcnt(3)" ::: "memory");
    } else {
      asm volatile("s_waitcnt vmcnt(0)" ::: "memory");
    }
    __builtin_amdgcn_sched_barrier(0);
    __builtin_amdgcn_s_barrier();
    __builtin_amdgcn_sched_barrier(0);
    const char* Ab = (const char*)Alds[kt & 1];
    const char* Bb = (const char*)Blds[kt & 1];
    bf16x8 af[4], bfv[4];
#pragma unroll
    for (int mi = 0; mi < 4; ++mi) {
      int r = wr * 64 + mi * 16 + l15;
      af[mi] = *(const bf16x8*)(Ab + r * 64 + ((l4 * 16) ^ (((r >> 1) & 3) << 4)));
    }
#pragma unroll
    for (int nj = 0; nj < 4; ++nj) {
      int c = wc * 64 + nj * 16 + l15;
      bfv[nj] = *(const bf16x8*)(Bb + c * 64 + ((l4 * 16) ^ (((c >> 1) & 3) << 4)));
    }
#pragma unroll
    for (int mi = 0; mi < 4; ++mi)
#pragma unroll
      for (int nj = 0; nj < 4; ++nj)
        acc[mi][nj] =
            __builtin_amdgcn_mfma_f32_16x16x32_bf16(af[mi], bfv[nj], acc[mi][nj], 0, 0, 0);
    __builtin_amdgcn_sched_barrier(0);
    __builtin_amdgcn_s_barrier();
  }
#pragma unroll
  for (int mi = 0; mi < 4; ++mi) {
    int rbase = m0 + wr * 64 + mi * 16 + l4 * 4;
#pragma unroll
    for (int nj = 0; nj < 4; ++nj) {
      int col = wc * 64 + nj * 16 + l15;
      float bv = bias[col];
#pragma unroll
      for (int r2 = 0; r2 < 4; ++r2) {
        int row = rbase + r2;
        if (row < NN) {
          float v = acc[mi][nj][r2] + bv;
          if (relu) v = fmaxf(v, 0.f);
          Y[row * 256 + col] = f2bf(v);
        }
      }
    }
  }
}

// ---------------- output projection (batched): he @ {Wr,Wn} -> Y4self/Y4nb ---
__global__ __launch_bounds__(256) void k_outproj(
    const u16* __restrict__ heb, size_t hes, const float* __restrict__ oWr,
    const float* __restrict__ oWn, int e0, float* __restrict__ Y4self,
    float* __restrict__ Y4nb) {
  __shared__ float Ws[256 * 4];
  int eabs = e0 + blockIdx.y;
  const u16* he = heb + (size_t)blockIdx.y * hes;
  const float* Wr = oWr + eabs * 512;
  const float* Wn = oWn + eabs * 512;
  int tid = threadIdx.x;
  Ws[tid * 4 + 0] = Wr[tid * 2];
  Ws[tid * 4 + 1] = Wr[tid * 2 + 1];
  Ws[tid * 4 + 2] = Wn[tid * 2];
  Ws[tid * 4 + 3] = Wn[tid * 2 + 1];
  __syncthreads();
  int wave = tid >> 6, lane = tid & 63;
  int node = blockIdx.x * 4 + wave;
  if (node >= NN) return;
  const u16* hrow = he + node * 256;
  int k0 = lane * 4;
  ushort4 hv4 = *(const ushort4*)(hrow + k0);
  float hv[4] = {bf2f(hv4.x), bf2f(hv4.y), bf2f(hv4.z), bf2f(hv4.w)};
  float a0 = 0.f, a1 = 0.f, a2 = 0.f, a3 = 0.f;
#pragma unroll
  for (int t = 0; t < 4; ++t) {
    float hvv = hv[t];
    const float* w = Ws + (k0 + t) * 4;
    a0 += hvv * w[0];
    a1 += hvv * w[1];
    a2 += hvv * w[2];
    a3 += hvv * w[3];
  }
#pragma unroll
  for (int off = 32; off > 0; off >>= 1) {
    a0 += __shfl_down(a0, off);
    a1 += __shfl_down(a1, off);
    a2 += __shfl_down(a2, off);
    a3 += __shfl_down(a3, off);
  }
  if (lane == 0) {
    Y4self[node * 16 + eabs * 2] = a0;
    Y4self[node * 16 + eabs * 2 + 1] = a1;
    Y4nb[node * 16 + eabs * 2] = a2;
    Y4nb[node * 16 + eabs * 2 + 1] = a3;
  }
}

// ---------------- single-pass combine over all 8 experts ---------------------
// thread (d,e): out[d] = sum_e sparse[d,e]*(Y4self[d][e] + sum_nb Y4nb[s][e] + ob[e])
__global__ __launch_bounds__(256) void k_combine(
    const int* __restrict__ rowptr, const int* __restrict__ csrc,
    const float* __restrict__ Y4self, const float* __restrict__ Y4nb,
    const float* __restrict__ sparse, const float* __restrict__ ob,
    float* __restrict__ out) {
  int t = blockIdx.x * 256 + threadIdx.x;
  int d = t >> 3, e = t & 7;
  if (d >= NN) return;
  float s0 = Y4self[d * 16 + e * 2], s1 = Y4self[d * 16 + e * 2 + 1];
  float n0 = 0.f, n1 = 0.f;
  for (int i = rowptr[d]; i < rowptr[d + 1]; ++i) {
    int s = csrc[i];
    float2 v = *(const float2*)(Y4nb + s * 16 + e * 2);  // 8 e-lanes: 64B coalesced
    n0 += v.x;
    n1 += v.y;
  }
  float w = sparse[d * 8 + e];
  float t0 = w * (s0 + n0 + ob[e * 2]);
  float t1 = w * (s1 + n1 + ob[e * 2 + 1]);
  t0 += __shfl_xor(t0, 1); t1 += __shfl_xor(t1, 1);
  t0 += __shfl_xor(t0, 2); t1 += __shfl_xor(t1, 2);
  t0 += __shfl_xor(t0, 4); t1 += __shfl_xor(t1, 4);
  if (e == 0) {
    out[d * 2] = t0;
    out[d * 2 + 1] = t1;
  }
}

extern "C" void kernel_launch(void* const* d_in, const int* in_sizes, int n_in,
                              void* d_out, int out_size, void* d_ws, size_t ws_size,
                              hipStream_t stream) {
  const float* x = (const float*)d_in[0];
  const int* ei = (const int*)d_in[1];
  const int* batch = (const int*)d_in[2];
  const float* enc_W = (const float*)d_in[3];
  const float* enc_b = (const float*)d_in[4];
  const float* rW1 = (const float*)d_in[5];
  const float* rb1 = (const float*)d_in[6];
  const float* rW2 = (const float*)d_in[7];
  const float* rb2 = (const float*)d_in[8];
  const float* hid_Wr = (const float*)d_in[9];
  const float* hid_Wn = (const float*)d_in[10];
  const float* hid_b = (const float*)d_in[11];
  const float* out_Wr = (const float*)d_in[12];
  const float* out_Wn = (const float*)d_in[13];
  const float* out_b = (const float*)d_in[14];
  float* out = (float*)d_out;

  char* ws = (char*)d_ws;
  size_t off = 0;
  auto alloc = [&](size_t bytes) -> void* {
    void* p = ws + off;
    off = (off + bytes + 511) & ~(size_t)511;
    return p;
  };
  const size_t HBYTES = (size_t)NN * 256 * 2;      // 25.6 MB
  u16* hb = (u16*)alloc(HBYTES);
  u16* agg0 = (u16*)alloc(HBYTES);
  u16* WrT = (u16*)alloc((size_t)24 * 65536 * 2);  // 3.15 MB
  u16* WnT = (u16*)alloc((size_t)24 * 65536 * 2);
  int* deg = (int*)alloc((size_t)NN * 4);
  int* rowptr = (int*)alloc((size_t)(NN + 1) * 4);
  int* cursor = (int*)alloc((size_t)NN * 4);
  int* outdeg = (int*)alloc((size_t)NN * 4);
  int* csrc = (int*)alloc((size_t)EE * 4);  // 3.2 MB
  float* gf = (float*)alloc(GG * 2 * 4);
  float* sparse = (float*)alloc((size_t)NN * 8 * 4);   // 1.6 MB
  float* Y4self = (float*)alloc((size_t)NN * 16 * 4);  // 3.2 MB
  float* Y4nb = (float*)alloc((size_t)NN * 16 * 4);    // 3.2 MB

  // Expert group size: he+agg pair = 51.2 MB per expert. Cap at 4 (L3 comfort).
  size_t rem = (ws_size > off) ? ws_size - off : 0;
  size_t per = 2 * HBYTES + 2048;
  int grp = (rem >= 4 * per) ? 4 : (rem >= 2 * per) ? 2 : (rem >= per) ? 1 : 0;
  if (grp == 0) {
    k_sentinel<<<1, 2, 0, stream>>>(out);
    return;
  }
  u16* heb = (u16*)alloc((size_t)grp * HBYTES);
  u16* aggb = (u16*)alloc((size_t)grp * HBYTES);

  hipMemsetAsync(deg, 0, (size_t)NN * 4, stream);
  hipMemsetAsync(cursor, 0, (size_t)NN * 4, stream);
  hipMemsetAsync(outdeg, 0, (size_t)NN * 4, stream);

  k_encoder<<<(NN * 256 + 255) / 256, 256, 0, stream>>>(x, enc_W, enc_b, hb);
  k_transpose<<<(24 * 65536 + 255) / 256, 256, 0, stream>>>(hid_Wr, WrT, 24);
  k_transpose<<<(24 * 65536 + 255) / 256, 256, 0, stream>>>(hid_Wn, WnT, 24);
  k_outdeg<<<(EE + 255) / 256, 256, 0, stream>>>(ei, outdeg);
  k_graph_feats<<<GG, 256, 0, stream>>>(batch, outdeg, gf);
  k_router<<<NN / 8, 256, 0, stream>>>(x, enc_W, enc_b, batch, gf, rW1, rb1, rW2, rb2, sparse);
  k_deg<<<(EE + 255) / 256, 256, 0, stream>>>(ei + EE, deg);
  k_scan<<<1, 1024, 0, stream>>>(deg, rowptr);
  k_fill<<<(EE + 255) / 256, 256, 0, stream>>>(ei, rowptr, cursor, csrc);

  const int GX = (NN + 127) / 128;       // 391 gemm blocks per expert
  const int SX = (NN + 3) / 4;           // 12500 spmm blocks per expert
  const size_t HS = (size_t)NN * 256;    // element stride per expert

  // shared layer-0 aggregation of h (identical input for every expert)
  k_spmm256<<<dim3(SX, 1), 256, 0, stream>>>(rowptr, csrc, hb, 0, agg0, 0);
  for (int e0 = 0; e0 < 8; e0 += grp) {
    // layer 0 (batched over grp experts): he = relu(hb@Wr + agg0@Wn + b)
    k_gemm<<<dim3(GX, grp), 512, 0, stream>>>(
        hb, 0, agg0, 0, WrT + e0 * 65536, WnT + e0 * 65536, 65536,
        hid_b + e0 * 256, 256, heb, HS, 1);
    for (int l = 1; l < 3; ++l) {
      k_spmm256<<<dim3(SX, grp), 256, 0, stream>>>(rowptr, csrc, heb, HS, aggb, HS);
      k_gemm<<<dim3(GX, grp), 512, 0, stream>>>(
          heb, HS, aggb, HS, WrT + (l * 8 + e0) * 65536, WnT + (l * 8 + e0) * 65536, 65536,
          hid_b + (l * 8 + e0) * 256, 256, heb, HS, 1);
    }
    k_outproj<<<dim3(SX, grp), 256, 0, stream>>>(heb, HS, out_Wr, out_Wn, e0, Y4self, Y4nb);
  }
  k_combine<<<(NN * 8 + 255) / 256, 256, 0, stream>>>(rowptr, csrc, Y4self, Y4nb, sparse,
                                                      out_b, out);
}

// Round 5
// 2313.309 us; speedup vs baseline: 1.1761x; 1.0889x over previous
//
#include <hip/hip_runtime.h>
#include <cstdint>

#define NN 50000
#define EE 800000
#define GG 64

typedef unsigned short u16;
typedef __attribute__((ext_vector_type(8))) short bf16x8;
typedef __attribute__((ext_vector_type(4))) float f32x4;

__device__ __forceinline__ float bf2f(u16 v) { return __uint_as_float(((unsigned)v) << 16); }
__device__ __forceinline__ u16 f2bf(float f) {
  unsigned u = __float_as_uint(f);
  return (u16)((u + 0x7fffu + ((u >> 16) & 1u)) >> 16);
}

__device__ __forceinline__ void gload_lds16(const void* g, void* l) {
  __builtin_amdgcn_global_load_lds(
      (const __attribute__((address_space(1))) void*)g,
      (__attribute__((address_space(3))) void*)l,
      16, 0, 0);
}

__global__ void k_sentinel(float* out) { out[threadIdx.x] = 1e12f; }

// ---------------- encoder: hb = bf16(relu(x @ enc_W + b)) --------------------
__global__ __launch_bounds__(256) void k_encoder(
    const float* __restrict__ x, const float* __restrict__ W,
    const float* __restrict__ b, u16* __restrict__ hb) {
  int idx = blockIdx.x * 256 + threadIdx.x;
  if (idx >= NN * 256) return;
  int row = idx >> 8, j = idx & 255;
  float s = b[j];
#pragma unroll
  for (int k = 0; k < 6; ++k) s += x[row * 6 + k] * W[k * 256 + j];
  hb[idx] = f2bf(fmaxf(s, 0.f));
}

// ---------------- merged histograms: in-degree (dst) + out-degree (src) ------
__global__ __launch_bounds__(256) void k_hist(const int* __restrict__ ei,
                                              int* __restrict__ deg,
                                              int* __restrict__ outdeg) {
  int i = blockIdx.x * 256 + threadIdx.x;
  if (i < EE) {
    atomicAdd(&outdeg[ei[i]], 1);
    atomicAdd(&deg[ei[EE + i]], 1);
  }
}

// one block per graph: binary-search boundaries in sorted batch, reduce outdeg.
__global__ __launch_bounds__(256) void k_graph_feats(const int* __restrict__ batch,
                                                     const int* __restrict__ outdeg,
                                                     float* __restrict__ gf) {
  __shared__ int red[256];
  int g = blockIdx.x, tid = threadIdx.x;
  auto lb = [&](int v) {
    int lo = 0, hi = NN;
    while (lo < hi) { int m = (lo + hi) >> 1; if (batch[m] < v) lo = m + 1; else hi = m; }
    return lo;
  };
  int bs = lb(g), be = lb(g + 1);
  int s = 0;
  for (int i = bs + tid; i < be; i += 256) s += outdeg[i];
  red[tid] = s;
  __syncthreads();
  for (int off = 128; off > 0; off >>= 1) {
    if (tid < off) red[tid] += red[tid + off];
    __syncthreads();
  }
  if (tid == 0) {
    gf[g * 2] = logf((float)(be - bs) + 1.f);
    gf[g * 2 + 1] = logf((float)red[0] + 1.f);
  }
}

// ---------------- router v3 (fp32; unrolled stage-1, parallel stage-2) -------
__global__ __launch_bounds__(256) void k_router(
    const float* __restrict__ x, const float* __restrict__ encW, const float* __restrict__ encb,
    const int* __restrict__ batch, const float* __restrict__ gf,
    const float* __restrict__ W1, const float* __restrict__ b1,
    const float* __restrict__ W2, const float* __restrict__ b2,
    float* __restrict__ sparse) {
  __shared__ __align__(16) float hs_t[258][8];  // k-major: row k holds h[0..7][k]
  __shared__ __align__(16) float rs_t[256][8];
  __shared__ float part2[4][64];
  __shared__ float xv[8][6];
  __shared__ float sf[8][2];
  __shared__ float lg[8][8];
  int tid = threadIdx.x;
  int nb = blockIdx.x * 8;
  if (tid < 48) {
    int r = tid / 6, k = tid % 6;
    int node = nb + r;
    xv[r][k] = (node < NN) ? x[node * 6 + k] : 0.f;
  }
  if (tid >= 48 && tid < 56) {
    int r = tid - 48;
    int node = nb + r;
    int g = (node < NN) ? batch[node] : 0;
    sf[r][0] = gf[g * 2];
    sf[r][1] = gf[g * 2 + 1];
  }
  __syncthreads();
  {
    float wcol[6];
#pragma unroll
    for (int k = 0; k < 6; ++k) wcol[k] = encW[k * 256 + tid];
    float bb = encb[tid];
#pragma unroll
    for (int r = 0; r < 8; ++r) {
      float s = bb;
#pragma unroll
      for (int k = 0; k < 6; ++k) s += xv[r][k] * wcol[k];
      hs_t[tid][r] = fmaxf(s, 0.f);
    }
  }
  if (tid < 16) {  // rows 256,257 = size feats
    int r = tid >> 1, c = tid & 1;
    hs_t[256 + c][r] = sf[r][c];
  }
  __syncthreads();
  float acc[8];
  {
    float bb = b1[tid];
#pragma unroll
    for (int r = 0; r < 8; ++r) acc[r] = bb;
  }
  int k = 0;
#pragma unroll 4
  for (; k < 256; ++k) {
    float w = W1[k * 256 + tid];
    float4 ha = *(const float4*)&hs_t[k][0];  // wave-uniform addr -> broadcast
    float4 hb4 = *(const float4*)&hs_t[k][4];
    acc[0] += ha.x * w; acc[1] += ha.y * w; acc[2] += ha.z * w; acc[3] += ha.w * w;
    acc[4] += hb4.x * w; acc[5] += hb4.y * w; acc[6] += hb4.z * w; acc[7] += hb4.w * w;
  }
  for (; k < 258; ++k) {
    float w = W1[k * 256 + tid];
    float4 ha = *(const float4*)&hs_t[k][0];
    float4 hb4 = *(const float4*)&hs_t[k][4];
    acc[0] += ha.x * w; acc[1] += ha.y * w; acc[2] += ha.z * w; acc[3] += ha.w * w;
    acc[4] += hb4.x * w; acc[5] += hb4.y * w; acc[6] += hb4.z * w; acc[7] += hb4.w * w;
  }
#pragma unroll
  for (int r = 0; r < 8; ++r) rs_t[tid][r] = fmaxf(acc[r], 0.f);
  __syncthreads();
  {  // stage 2: all 256 threads; pair=(r,e)=tid&63, k-part=tid>>6
    int pr = tid & 63, pt = tid >> 6;
    int r = pr >> 3, e = pr & 7;
    float s = 0.f;
    int kk0 = pt * 64;
#pragma unroll 4
    for (int kk = kk0; kk < kk0 + 64; ++kk) s += rs_t[kk][r] * W2[kk * 8 + e];
    part2[pt][pr] = s;
  }
  __syncthreads();
  if (tid < 64) {
    int r = tid >> 3, e = tid & 7;
    lg[r][e] = b2[e] + part2[0][tid] + part2[1][tid] + part2[2][tid] + part2[3][tid];
  }
  __syncthreads();
  if (tid < 8) {
    int node = nb + tid;
    if (node < NN) {
      float v1 = lg[tid][0];
      int j1 = 0;
#pragma unroll
      for (int j = 1; j < 8; ++j) {
        float v = lg[tid][j];
        if (v > v1) { v1 = v; j1 = j; }
      }
      float v2 = -1e30f;
      int j2 = 0;
#pragma unroll
      for (int j = 0; j < 8; ++j) {
        if (j == j1) continue;
        float v = lg[tid][j];
        if (v > v2) { v2 = v; j2 = j; }
      }
      float ex = expf(v2 - v1);
      float wa = 1.f / (1.f + ex), wb = ex / (1.f + ex);
      float* sp = sparse + node * 8;
#pragma unroll
      for (int j = 0; j < 8; ++j) sp[j] = 0.f;
      sp[j1] = wa;
      sp[j2] = wb;
    }
  }
}

// ---------------- CSR build (by dst) -----------------------------------------
__global__ __launch_bounds__(1024) void k_scan(const int* __restrict__ deg,
                                               int* __restrict__ rowptr) {
  __shared__ int tmp[1024];
  __shared__ int carry;
  if (threadIdx.x == 0) { carry = 0; rowptr[0] = 0; }
  __syncthreads();
  for (int base = 0; base < NN; base += 1024) {
    int i = base + threadIdx.x;
    int v = (i < NN) ? deg[i] : 0;
    tmp[threadIdx.x] = v;
    __syncthreads();
    for (int off = 1; off < 1024; off <<= 1) {
      int t = (threadIdx.x >= off) ? tmp[threadIdx.x - off] : 0;
      __syncthreads();
      tmp[threadIdx.x] += t;
      __syncthreads();
    }
    if (i < NN) rowptr[i + 1] = carry + tmp[threadIdx.x];
    int last = tmp[1023];
    __syncthreads();
    if (threadIdx.x == 0) carry += last;
    __syncthreads();
  }
}

__global__ __launch_bounds__(256) void k_fill(const int* __restrict__ ei,
                                              const int* __restrict__ rowptr,
                                              int* __restrict__ cursor, int* __restrict__ csrc) {
  int i = blockIdx.x * 256 + threadIdx.x;
  if (i < EE) {
    int s = ei[i], d = ei[EE + i];
    int pos = atomicAdd(&cursor[d], 1);
    csrc[rowptr[d] + pos] = s;
  }
}

// ---------------- SpMM (expert-batched): Y[g][d] = sum X[g][src[e]] ----------
__global__ __launch_bounds__(256) void k_spmm256(
    const int* __restrict__ rowptr, const int* __restrict__ csrc,
    const u16* __restrict__ Xb, size_t xs, u16* __restrict__ Yb, size_t ys) {
  const u16* X = Xb + (size_t)blockIdx.y * xs;
  u16* Y = Yb + (size_t)blockIdx.y * ys;
  int wave = threadIdx.x >> 6, lane = threadIdx.x & 63;
  int d = blockIdx.x * 4 + wave;
  if (d >= NN) return;
  int s0 = rowptr[d], s1 = rowptr[d + 1];
  int c4 = lane * 4;
  float a0 = 0.f, a1 = 0.f, a2 = 0.f, a3 = 0.f;
  int i = s0;
  for (; i + 2 <= s1; i += 2) {
    int sa = csrc[i], sb = csrc[i + 1];
    ushort4 va = *(const ushort4*)(X + sa * 256 + c4);
    ushort4 vb = *(const ushort4*)(X + sb * 256 + c4);
    a0 += bf2f(va.x) + bf2f(vb.x);
    a1 += bf2f(va.y) + bf2f(vb.y);
    a2 += bf2f(va.z) + bf2f(vb.z);
    a3 += bf2f(va.w) + bf2f(vb.w);
  }
  if (i < s1) {
    int sa = csrc[i];
    ushort4 va = *(const ushort4*)(X + sa * 256 + c4);
    a0 += bf2f(va.x);
    a1 += bf2f(va.y);
    a2 += bf2f(va.z);
    a3 += bf2f(va.w);
  }
  ushort4 o;
  o.x = f2bf(a0); o.y = f2bf(a1); o.z = f2bf(a2); o.w = f2bf(a3);
  *(ushort4*)(Y + d * 256 + c4) = o;
}

// ------------- weight transpose+bf16 (both stacks): W[m][k][j] -> Wt[m][j][k] -
__global__ __launch_bounds__(256) void k_transpose2(const float* __restrict__ Wr,
                                                    const float* __restrict__ Wn,
                                                    u16* __restrict__ WrT,
                                                    u16* __restrict__ WnT) {
  int idx = blockIdx.x * 256 + threadIdx.x;
  if (idx >= 24 * 65536) return;
  int m = idx >> 16, rem = idx & 65535;
  int k = rem >> 8, j = rem & 255;
  int o = (m << 16) + (j << 8) + k;
  WrT[o] = f2bf(Wr[idx]);
  WnT[o] = f2bf(Wn[idx]);
}

// ---------------- fused dual-source MFMA GEMM (expert-batched) ---------------
// Y[g][m,0:256] = act( X1[g][m,:]@W1t[g]^T + X2[g][m,:]@W2t[g]^T + bias[g] )
// do_out: instead of writing Y, apply out-projection (H->2+2) in-register and
// write Y4self/Y4nb (self = he2@oWr, nb = he2@oWn, fp32).
__global__ __launch_bounds__(512) void k_gemm(
    const u16* __restrict__ X1b, size_t x1s, const u16* __restrict__ X2b, size_t x2s,
    const u16* __restrict__ W1tb, const u16* __restrict__ W2tb, size_t wst,
    const float* __restrict__ biasb, size_t bst,
    u16* __restrict__ Yb, size_t yst, int relu,
    const float* __restrict__ oWr, const float* __restrict__ oWn, int e0_base,
    float* __restrict__ Y4self, float* __restrict__ Y4nb, int do_out) {
  __shared__ __align__(16) char smem[49152];  // A dbuf 16KB | B dbuf 32KB; epilogue reuses
  int g = blockIdx.y;
  const u16* X1 = X1b + (size_t)g * x1s;
  const u16* X2 = X2b + (size_t)g * x2s;
  const u16* W1t = W1tb + (size_t)g * wst;
  const u16* W2t = W2tb + (size_t)g * wst;
  const float* bias = biasb + (size_t)g * bst;
  u16* Y = Yb + (size_t)g * yst;
  int tid = threadIdx.x;
  int wave = tid >> 6, lane = tid & 63;
  int l15 = lane & 15, l4 = lane >> 4;
  int m0 = blockIdx.x * 128;
  int wr = wave >> 2, wc = wave & 3;
  const f32x4 fz = {0.f, 0.f, 0.f, 0.f};
  f32x4 acc[4][4];
#pragma unroll
  for (int a = 0; a < 4; ++a)
#pragma unroll
    for (int b = 0; b < 4; ++b) acc[a][b] = fz;

  auto stage = [&](int t) {
    const u16* xs = (t < 8) ? X1 : X2;
    const u16* wsrc = (t < 8) ? W1t : W2t;
    int kb = (t & 7) * 32;
    int half = t & 1;
    {
      int flat = wave * 1024 + lane * 16;
      int row = flat >> 6, colb = flat & 63;
      int scol = colb ^ (((row >> 1) & 3) << 4);  // inverse-swizzle the SOURCE
      int gr = m0 + row;
      if (gr > NN - 1) gr = NN - 1;
      gload_lds16(xs + gr * 256 + kb + (scol >> 1), smem + half * 8192 + flat);
    }
#pragma unroll
    for (int q = 0; q < 2; ++q) {
      int flat = q * 8192 + wave * 1024 + lane * 16;
      int row = flat >> 6, colb = flat & 63;
      int scol = colb ^ (((row >> 1) & 3) << 4);
      gload_lds16(wsrc + row * 256 + kb + (scol >> 1), smem + 16384 + half * 16384 + flat);
    }
  };

  stage(0);
  for (int kt = 0; kt < 16; ++kt) {
    if (kt < 15) {
      stage(kt + 1);
      asm volatile("s_waitcnt vmcnt(3)" ::: "memory");
    } else {
      asm volatile("s_waitcnt vmcnt(0)" ::: "memory");
    }
    __builtin_amdgcn_sched_barrier(0);
    __builtin_amdgcn_s_barrier();
    __builtin_amdgcn_sched_barrier(0);
    const char* Ab = smem + (kt & 1) * 8192;
    const char* Bb = smem + 16384 + (kt & 1) * 16384;
    bf16x8 af[4], bfv[4];
#pragma unroll
    for (int mi = 0; mi < 4; ++mi) {
      int r = wr * 64 + mi * 16 + l15;
      af[mi] = *(const bf16x8*)(Ab + r * 64 + ((l4 * 16) ^ (((r >> 1) & 3) << 4)));
    }
#pragma unroll
    for (int nj = 0; nj < 4; ++nj) {
      int c = wc * 64 + nj * 16 + l15;
      bfv[nj] = *(const bf16x8*)(Bb + c * 64 + ((l4 * 16) ^ (((c >> 1) & 3) << 4)));
    }
#pragma unroll
    for (int mi = 0; mi < 4; ++mi)
#pragma unroll
      for (int nj = 0; nj < 4; ++nj)
        acc[mi][nj] =
            __builtin_amdgcn_mfma_f32_16x16x32_bf16(af[mi], bfv[nj], acc[mi][nj], 0, 0, 0);
    __builtin_amdgcn_sched_barrier(0);
    __builtin_amdgcn_s_barrier();
  }

  if (!do_out) {
    // epilogue: C/D map col=lane&15, row=(lane>>4)*4+reg  [m89-verified]
#pragma unroll
    for (int mi = 0; mi < 4; ++mi) {
      int rbase = m0 + wr * 64 + mi * 16 + l4 * 4;
#pragma unroll
      for (int nj = 0; nj < 4; ++nj) {
        int col = wc * 64 + nj * 16 + l15;
        float bv = bias[col];
#pragma unroll
        for (int r2 = 0; r2 < 4; ++r2) {
          int row = rbase + r2;
          if (row < NN) {
            float v = acc[mi][nj][r2] + bv;
            if (relu) v = fmaxf(v, 0.f);
            Y[row * 256 + col] = f2bf(v);
          }
        }
      }
    }
  } else {
    // fused out-projection: he2 = relu(acc+bias); Y4self/nb = he2 @ {oWr,oWn}
    int eabs = e0_base + g;
    const float2* wr2p = (const float2*)(oWr + (size_t)eabs * 512);
    const float2* wn2p = (const float2*)(oWn + (size_t)eabs * 512);
    float bv[4]; float2 wa[4], wb[4];
#pragma unroll
    for (int nj = 0; nj < 4; ++nj) {
      int col = wc * 64 + nj * 16 + l15;
      bv[nj] = bias[col];
      wa[nj] = wr2p[col];
      wb[nj] = wn2p[col];
    }
    float* y4red = (float*)smem;  // [128][4 wc][4] = 8KB (post-barrier reuse)
#pragma unroll
    for (int mi = 0; mi < 4; ++mi) {
#pragma unroll
      for (int r2 = 0; r2 < 4; ++r2) {
        float p0 = 0.f, p1 = 0.f, p2 = 0.f, p3 = 0.f;
#pragma unroll
        for (int nj = 0; nj < 4; ++nj) {
          float v = fmaxf(acc[mi][nj][r2] + bv[nj], 0.f);
          p0 += v * wa[nj].x; p1 += v * wa[nj].y;
          p2 += v * wb[nj].x; p3 += v * wb[nj].y;
        }
#pragma unroll
        for (int off2 = 1; off2 < 16; off2 <<= 1) {
          p0 += __shfl_xor(p0, off2); p1 += __shfl_xor(p1, off2);
          p2 += __shfl_xor(p2, off2); p3 += __shfl_xor(p3, off2);
        }
        if (l15 == 0) {
          int lr = wr * 64 + mi * 16 + l4 * 4 + r2;
          float* q = y4red + (lr * 4 + wc) * 4;
          q[0] = p0; q[1] = p1; q[2] = p2; q[3] = p3;
        }
      }
    }
    __syncthreads();
    if (tid < 128) {
      int row = m0 + tid;
      if (row < NN) {
        float s0 = 0.f, s1 = 0.f, n0 = 0.f, n1 = 0.f;
#pragma unroll
        for (int w2 = 0; w2 < 4; ++w2) {
          const float* q = y4red + (tid * 4 + w2) * 4;
          s0 += q[0]; s1 += q[1]; n0 += q[2]; n1 += q[3];
        }
        Y4self[row * 16 + eabs * 2] = s0;
        Y4self[row * 16 + eabs * 2 + 1] = s1;
        Y4nb[row * 16 + eabs * 2] = n0;
        Y4nb[row * 16 + eabs * 2 + 1] = n1;
      }
    }
  }
}

// ---------------- single-pass combine over all 8 experts ---------------------
__global__ __launch_bounds__(256) void k_combine(
    const int* __restrict__ rowptr, const int* __restrict__ csrc,
    const float* __restrict__ Y4self, const float* __restrict__ Y4nb,
    const float* __restrict__ sparse, const float* __restrict__ ob,
    float* __restrict__ out) {
  int t = blockIdx.x * 256 + threadIdx.x;
  int d = t >> 3, e = t & 7;
  if (d >= NN) return;
  float s0 = Y4self[d * 16 + e * 2], s1 = Y4self[d * 16 + e * 2 + 1];
  float n0 = 0.f, n1 = 0.f;
  for (int i = rowptr[d]; i < rowptr[d + 1]; ++i) {
    int s = csrc[i];
    float2 v = *(const float2*)(Y4nb + s * 16 + e * 2);  // 8 e-lanes: 64B coalesced
    n0 += v.x;
    n1 += v.y;
  }
  float w = sparse[d * 8 + e];
  float t0 = w * (s0 + n0 + ob[e * 2]);
  float t1 = w * (s1 + n1 + ob[e * 2 + 1]);
  t0 += __shfl_xor(t0, 1); t1 += __shfl_xor(t1, 1);
  t0 += __shfl_xor(t0, 2); t1 += __shfl_xor(t1, 2);
  t0 += __shfl_xor(t0, 4); t1 += __shfl_xor(t1, 4);
  if (e == 0) {
    out[d * 2] = t0;
    out[d * 2 + 1] = t1;
  }
}

extern "C" void kernel_launch(void* const* d_in, const int* in_sizes, int n_in,
                              void* d_out, int out_size, void* d_ws, size_t ws_size,
                              hipStream_t stream) {
  const float* x = (const float*)d_in[0];
  const int* ei = (const int*)d_in[1];
  const int* batch = (const int*)d_in[2];
  const float* enc_W = (const float*)d_in[3];
  const float* enc_b = (const float*)d_in[4];
  const float* rW1 = (const float*)d_in[5];
  const float* rb1 = (const float*)d_in[6];
  const float* rW2 = (const float*)d_in[7];
  const float* rb2 = (const float*)d_in[8];
  const float* hid_Wr = (const float*)d_in[9];
  const float* hid_Wn = (const float*)d_in[10];
  const float* hid_b = (const float*)d_in[11];
  const float* out_Wr = (const float*)d_in[12];
  const float* out_Wn = (const float*)d_in[13];
  const float* out_b = (const float*)d_in[14];
  float* out = (float*)d_out;

  char* ws = (char*)d_ws;
  size_t off = 0;
  auto alloc = [&](size_t bytes) -> void* {
    void* p = ws + off;
    off = (off + bytes + 511) & ~(size_t)511;
    return p;
  };
  const size_t HBYTES = (size_t)NN * 256 * 2;      // 25.6 MB
  u16* hb = (u16*)alloc(HBYTES);
  u16* agg0 = (u16*)alloc(HBYTES);
  u16* WrT = (u16*)alloc((size_t)24 * 65536 * 2);  // 3.15 MB
  u16* WnT = (u16*)alloc((size_t)24 * 65536 * 2);
  // contiguous zero region: deg | cursor | outdeg
  int* deg = (int*)alloc((size_t)NN * 4);
  int* cursor = (int*)alloc((size_t)NN * 4);
  int* outdeg = (int*)alloc((size_t)NN * 4);
  size_t zero_bytes = (size_t)((char*)(outdeg + NN) - (char*)deg);
  int* rowptr = (int*)alloc((size_t)(NN + 1) * 4);
  int* csrc = (int*)alloc((size_t)EE * 4);  // 3.2 MB
  float* gf = (float*)alloc(GG * 2 * 4);
  float* sparse = (float*)alloc((size_t)NN * 8 * 4);   // 1.6 MB
  float* Y4self = (float*)alloc((size_t)NN * 16 * 4);  // 3.2 MB
  float* Y4nb = (float*)alloc((size_t)NN * 16 * 4);    // 3.2 MB

  // Expert group size: he+agg pair = 51.2 MB per expert. Cap at 4 (L3 comfort).
  size_t rem = (ws_size > off) ? ws_size - off : 0;
  size_t per = 2 * HBYTES + 2048;
  int grp = (rem >= 4 * per) ? 4 : (rem >= 2 * per) ? 2 : (rem >= per) ? 1 : 0;
  if (grp == 0) {
    k_sentinel<<<1, 2, 0, stream>>>(out);
    return;
  }
  u16* heb = (u16*)alloc((size_t)grp * HBYTES);
  u16* aggb = (u16*)alloc((size_t)grp * HBYTES);

  hipMemsetAsync(deg, 0, zero_bytes, stream);

  k_encoder<<<(NN * 256 + 255) / 256, 256, 0, stream>>>(x, enc_W, enc_b, hb);
  k_transpose2<<<(24 * 65536 + 255) / 256, 256, 0, stream>>>(hid_Wr, hid_Wn, WrT, WnT);
  k_hist<<<(EE + 255) / 256, 256, 0, stream>>>(ei, deg, outdeg);
  k_graph_feats<<<GG, 256, 0, stream>>>(batch, outdeg, gf);
  k_scan<<<1, 1024, 0, stream>>>(deg, rowptr);
  k_fill<<<(EE + 255) / 256, 256, 0, stream>>>(ei, rowptr, cursor, csrc);
  k_router<<<NN / 8, 256, 0, stream>>>(x, enc_W, enc_b, batch, gf, rW1, rb1, rW2, rb2, sparse);

  const int GX = (NN + 127) / 128;     // 391 gemm blocks per expert
  const int SX = (NN + 3) / 4;         // 12500 spmm blocks per expert
  const size_t HS = (size_t)NN * 256;  // element stride per expert

  // shared layer-0 aggregation of h (identical input for every expert)
  k_spmm256<<<dim3(SX, 1), 256, 0, stream>>>(rowptr, csrc, hb, 0, agg0, 0);
  for (int e0 = 0; e0 < 8; e0 += grp) {
    // layer 0 (batched over grp experts)
    k_gemm<<<dim3(GX, grp), 512, 0, stream>>>(
        hb, 0, agg0, 0, WrT + e0 * 65536, WnT + e0 * 65536, 65536,
        hid_b + e0 * 256, 256, heb, HS, 1, nullptr, nullptr, 0, nullptr, nullptr, 0);
    // layer 1
    k_spmm256<<<dim3(SX, grp), 256, 0, stream>>>(rowptr, csrc, heb, HS, aggb, HS);
    k_gemm<<<dim3(GX, grp), 512, 0, stream>>>(
        heb, HS, aggb, HS, WrT + (8 + e0) * 65536, WnT + (8 + e0) * 65536, 65536,
        hid_b + (8 + e0) * 256, 256, heb, HS, 1, nullptr, nullptr, 0, nullptr, nullptr, 0);
    // layer 2 + fused out-projection
    k_spmm256<<<dim3(SX, grp), 256, 0, stream>>>(rowptr, csrc, heb, HS, aggb, HS);
    k_gemm<<<dim3(GX, grp), 512, 0, stream>>>(
        heb, HS, aggb, HS, WrT + (16 + e0) * 65536, WnT + (16 + e0) * 65536, 65536,
        hid_b + (16 + e0) * 256, 256, heb, HS, 1, out_Wr, out_Wn, e0, Y4self, Y4nb, 1);
  }
  k_combine<<<(NN * 8 + 255) / 256, 256, 0, stream>>>(rowptr, csrc, Y4self, Y4nb, sparse,
                                                      out_b, out);
}

// Round 6
// 2248.636 us; speedup vs baseline: 1.2099x; 1.0288x over previous
//
#include <hip/hip_runtime.h>
#include <cstdint>

#define NN 50000
#define EE 800000
#define GG 64

typedef unsigned short u16;
typedef __attribute__((ext_vector_type(8))) short bf16x8;
typedef __attribute__((ext_vector_type(4))) float f32x4;

__device__ __forceinline__ float bf2f(u16 v) { return __uint_as_float(((unsigned)v) << 16); }
__device__ __forceinline__ u16 f2bf(float f) {
  unsigned u = __float_as_uint(f);
  return (u16)((u + 0x7fffu + ((u >> 16) & 1u)) >> 16);
}

__device__ __forceinline__ void gload_lds16(const void* g, void* l) {
  __builtin_amdgcn_global_load_lds(
      (const __attribute__((address_space(1))) void*)g,
      (__attribute__((address_space(3))) void*)l,
      16, 0, 0);
}

__global__ void k_sentinel(float* out) { out[threadIdx.x] = 1e12f; }

// ---------------- merged histograms: in-degree (dst) + out-degree (src) ------
__global__ __launch_bounds__(256) void k_hist(const int* __restrict__ ei,
                                              int* __restrict__ deg,
                                              int* __restrict__ outdeg) {
  int i = blockIdx.x * 256 + threadIdx.x;
  if (i < EE) {
    atomicAdd(&outdeg[ei[i]], 1);
    atomicAdd(&deg[ei[EE + i]], 1);
  }
}

// one block per graph: binary-search boundaries in sorted batch, reduce outdeg.
__global__ __launch_bounds__(256) void k_graph_feats(const int* __restrict__ batch,
                                                     const int* __restrict__ outdeg,
                                                     float* __restrict__ gf) {
  __shared__ int red[256];
  int g = blockIdx.x, tid = threadIdx.x;
  auto lb = [&](int v) {
    int lo = 0, hi = NN;
    while (lo < hi) { int m = (lo + hi) >> 1; if (batch[m] < v) lo = m + 1; else hi = m; }
    return lo;
  };
  int bs = lb(g), be = lb(g + 1);
  int s = 0;
  for (int i = bs + tid; i < be; i += 256) s += outdeg[i];
  red[tid] = s;
  __syncthreads();
  for (int off = 128; off > 0; off >>= 1) {
    if (tid < off) red[tid] += red[tid + off];
    __syncthreads();
  }
  if (tid == 0) {
    gf[g * 2] = logf((float)(be - bs) + 1.f);
    gf[g * 2 + 1] = logf((float)red[0] + 1.f);
  }
}

// ------- router v4 (fp32) + fused encoder output (hb = bf16(h)) --------------
__global__ __launch_bounds__(256) void k_router(
    const float* __restrict__ x, const float* __restrict__ encW, const float* __restrict__ encb,
    const int* __restrict__ batch, const float* __restrict__ gf,
    const float* __restrict__ W1, const float* __restrict__ b1,
    const float* __restrict__ W2, const float* __restrict__ b2,
    float* __restrict__ sparse, u16* __restrict__ hb_out) {
  __shared__ __align__(16) float hs_t[258][8];  // k-major: row k holds h[0..7][k]
  __shared__ __align__(16) float rs_t[256][8];
  __shared__ float part2[4][64];
  __shared__ float xv[8][6];
  __shared__ float sf[8][2];
  __shared__ float lg[8][8];
  int tid = threadIdx.x;
  int nb = blockIdx.x * 8;  // NN = 50000 = 6250*8 exact
  if (tid < 48) {
    int r = tid / 6, k = tid % 6;
    xv[r][k] = x[(nb + r) * 6 + k];
  }
  if (tid >= 48 && tid < 56) {
    int r = tid - 48;
    int g = batch[nb + r];
    sf[r][0] = gf[g * 2];
    sf[r][1] = gf[g * 2 + 1];
  }
  __syncthreads();
  {
    float wcol[6];
#pragma unroll
    for (int k = 0; k < 6; ++k) wcol[k] = encW[k * 256 + tid];
    float bb = encb[tid];
#pragma unroll
    for (int r = 0; r < 8; ++r) {
      float s = bb;
#pragma unroll
      for (int k = 0; k < 6; ++k) s += xv[r][k] * wcol[k];
      float h = fmaxf(s, 0.f);
      hs_t[tid][r] = h;
      hb_out[(nb + r) * 256 + tid] = f2bf(h);  // fused encoder output
    }
  }
  if (tid < 16) {  // rows 256,257 = size feats
    int r = tid >> 1, c = tid & 1;
    hs_t[256 + c][r] = sf[r][c];
  }
  __syncthreads();
  float acc[8];
  {
    float bb = b1[tid];
#pragma unroll
    for (int r = 0; r < 8; ++r) acc[r] = bb;
  }
  int k = 0;
#pragma unroll 4
  for (; k < 256; ++k) {
    float w = W1[k * 256 + tid];
    float4 ha = *(const float4*)&hs_t[k][0];  // wave-uniform addr -> broadcast
    float4 hb4 = *(const float4*)&hs_t[k][4];
    acc[0] += ha.x * w; acc[1] += ha.y * w; acc[2] += ha.z * w; acc[3] += ha.w * w;
    acc[4] += hb4.x * w; acc[5] += hb4.y * w; acc[6] += hb4.z * w; acc[7] += hb4.w * w;
  }
  for (; k < 258; ++k) {
    float w = W1[k * 256 + tid];
    float4 ha = *(const float4*)&hs_t[k][0];
    float4 hb4 = *(const float4*)&hs_t[k][4];
    acc[0] += ha.x * w; acc[1] += ha.y * w; acc[2] += ha.z * w; acc[3] += ha.w * w;
    acc[4] += hb4.x * w; acc[5] += hb4.y * w; acc[6] += hb4.z * w; acc[7] += hb4.w * w;
  }
#pragma unroll
  for (int r = 0; r < 8; ++r) rs_t[tid][r] = fmaxf(acc[r], 0.f);
  __syncthreads();
  {  // stage 2: all 256 threads; pair=(r,e)=tid&63, k-part=tid>>6
    int pr = tid & 63, pt = tid >> 6;
    int r = pr >> 3, e = pr & 7;
    float s = 0.f;
    int kk0 = pt * 64;
#pragma unroll 4
    for (int kk = kk0; kk < kk0 + 64; ++kk) s += rs_t[kk][r] * W2[kk * 8 + e];
    part2[pt][pr] = s;
  }
  __syncthreads();
  if (tid < 64) {
    int r = tid >> 3, e = tid & 7;
    lg[r][e] = b2[e] + part2[0][tid] + part2[1][tid] + part2[2][tid] + part2[3][tid];
  }
  __syncthreads();
  if (tid < 8) {
    int node = nb + tid;
    {
      float v1 = lg[tid][0];
      int j1 = 0;
#pragma unroll
      for (int j = 1; j < 8; ++j) {
        float v = lg[tid][j];
        if (v > v1) { v1 = v; j1 = j; }
      }
      float v2 = -1e30f;
      int j2 = 0;
#pragma unroll
      for (int j = 0; j < 8; ++j) {
        if (j == j1) continue;
        float v = lg[tid][j];
        if (v > v2) { v2 = v; j2 = j; }
      }
      float ex = expf(v2 - v1);
      float wa = 1.f / (1.f + ex), wb = ex / (1.f + ex);
      float* sp = sparse + node * 8;
#pragma unroll
      for (int j = 0; j < 8; ++j) sp[j] = 0.f;
      sp[j1] = wa;
      sp[j2] = wb;
    }
  }
}

// ---------------- CSR build (by dst) -----------------------------------------
__global__ __launch_bounds__(1024) void k_scan(const int* __restrict__ deg,
                                               int* __restrict__ rowptr) {
  __shared__ int tmp[1024];
  __shared__ int carry;
  if (threadIdx.x == 0) { carry = 0; rowptr[0] = 0; }
  __syncthreads();
  for (int base = 0; base < NN; base += 1024) {
    int i = base + threadIdx.x;
    int v = (i < NN) ? deg[i] : 0;
    tmp[threadIdx.x] = v;
    __syncthreads();
    for (int off = 1; off < 1024; off <<= 1) {
      int t = (threadIdx.x >= off) ? tmp[threadIdx.x - off] : 0;
      __syncthreads();
      tmp[threadIdx.x] += t;
      __syncthreads();
    }
    if (i < NN) rowptr[i + 1] = carry + tmp[threadIdx.x];
    int last = tmp[1023];
    __syncthreads();
    if (threadIdx.x == 0) carry += last;
    __syncthreads();
  }
}

__global__ __launch_bounds__(256) void k_fill(const int* __restrict__ ei,
                                              const int* __restrict__ rowptr,
                                              int* __restrict__ cursor, int* __restrict__ csrc) {
  int i = blockIdx.x * 256 + threadIdx.x;
  if (i < EE) {
    int s = ei[i], d = ei[EE + i];
    int pos = atomicAdd(&cursor[d], 1);
    csrc[rowptr[d] + pos] = s;
  }
}

// -------- SpMM, plain layout (layer-0 shared agg): wave per dst --------------
__global__ __launch_bounds__(256) void k_spmm256(
    const int* __restrict__ rowptr, const int* __restrict__ csrc,
    const u16* __restrict__ X, u16* __restrict__ Y) {
  int wave = threadIdx.x >> 6, lane = threadIdx.x & 63;
  int d = blockIdx.x * 4 + wave;
  if (d >= NN) return;
  int s0 = rowptr[d], s1 = rowptr[d + 1];
  int c4 = lane * 4;
  float a0 = 0.f, a1 = 0.f, a2 = 0.f, a3 = 0.f;
  int i = s0;
  for (; i + 2 <= s1; i += 2) {
    int sa = csrc[i], sb = csrc[i + 1];
    ushort4 va = *(const ushort4*)(X + sa * 256 + c4);
    ushort4 vb = *(const ushort4*)(X + sb * 256 + c4);
    a0 += bf2f(va.x) + bf2f(vb.x);
    a1 += bf2f(va.y) + bf2f(vb.y);
    a2 += bf2f(va.z) + bf2f(vb.z);
    a3 += bf2f(va.w) + bf2f(vb.w);
  }
  if (i < s1) {
    int sa = csrc[i];
    ushort4 va = *(const ushort4*)(X + sa * 256 + c4);
    a0 += bf2f(va.x);
    a1 += bf2f(va.y);
    a2 += bf2f(va.z);
    a3 += bf2f(va.w);
  }
  ushort4 o;
  o.x = f2bf(a0); o.y = f2bf(a1); o.z = f2bf(a2); o.w = f2bf(a3);
  *(ushort4*)(Y + d * 256 + c4) = o;
}

// -------- SpMM, expert-interleaved layout: block per dst, contiguous row -----
// X,Y: [node][rs] where rs = grp*256. One edge gather = rs*2 contiguous bytes.
__global__ __launch_bounds__(256) void k_spmm_intl(
    const int* __restrict__ rowptr, const int* __restrict__ csrc,
    const u16* __restrict__ X, u16* __restrict__ Y, int rs) {
  int d = blockIdx.x;
  int tid = threadIdx.x;
  if (tid * 4 >= rs) return;  // grp<4 fallback
  int s0 = rowptr[d], s1 = rowptr[d + 1];
  int c4 = tid * 4;
  float a0 = 0.f, a1 = 0.f, a2 = 0.f, a3 = 0.f;
  int i = s0;
  for (; i + 2 <= s1; i += 2) {
    int sa = csrc[i], sb = csrc[i + 1];
    ushort4 va = *(const ushort4*)(X + (size_t)sa * rs + c4);
    ushort4 vb = *(const ushort4*)(X + (size_t)sb * rs + c4);
    a0 += bf2f(va.x) + bf2f(vb.x);
    a1 += bf2f(va.y) + bf2f(vb.y);
    a2 += bf2f(va.z) + bf2f(vb.z);
    a3 += bf2f(va.w) + bf2f(vb.w);
  }
  if (i < s1) {
    int sa = csrc[i];
    ushort4 va = *(const ushort4*)(X + (size_t)sa * rs + c4);
    a0 += bf2f(va.x);
    a1 += bf2f(va.y);
    a2 += bf2f(va.z);
    a3 += bf2f(va.w);
  }
  ushort4 o;
  o.x = f2bf(a0); o.y = f2bf(a1); o.z = f2bf(a2); o.w = f2bf(a3);
  *(ushort4*)(Y + (size_t)d * rs + c4) = o;
}

// ------------- weight transpose+bf16 (both stacks): W[m][k][j] -> Wt[m][j][k] -
__global__ __launch_bounds__(256) void k_transpose2(const float* __restrict__ Wr,
                                                    const float* __restrict__ Wn,
                                                    u16* __restrict__ WrT,
                                                    u16* __restrict__ WnT) {
  int idx = blockIdx.x * 256 + threadIdx.x;
  if (idx >= 24 * 65536) return;
  int m = idx >> 16, rem = idx & 65535;
  int k = rem >> 8, j = rem & 255;
  int o = (m << 16) + (j << 8) + k;
  WrT[o] = f2bf(Wr[idx]);
  WnT[o] = f2bf(Wn[idx]);
}

// ---------------- fused dual-source MFMA GEMM (expert-batched, strided) ------
// Y[g][m,0:256] = act( X1[g][m,:]@W1t[g]^T + X2[g][m,:]@W2t[g]^T + bias[g] )
// X row i at Xb + g*gs + i*rs (rs in elements). Y likewise (ygs/yrs).
// do_out: apply out-projection (H->2+2) in-register, write Y4self/Y4nb.
__global__ __launch_bounds__(512) void k_gemm(
    const u16* __restrict__ X1b, size_t x1gs, int x1rs,
    const u16* __restrict__ X2b, size_t x2gs, int x2rs,
    const u16* __restrict__ W1tb, const u16* __restrict__ W2tb, size_t wst,
    const float* __restrict__ biasb, size_t bst,
    u16* __restrict__ Yb, size_t ygs, int yrs, int relu,
    const float* __restrict__ oWr, const float* __restrict__ oWn, int e0_base,
    float* __restrict__ Y4self, float* __restrict__ Y4nb, int do_out) {
  __shared__ __align__(16) char smem[49152];  // A dbuf 16KB | B dbuf 32KB
  int g = blockIdx.y;
  const u16* X1 = X1b + (size_t)g * x1gs;
  const u16* X2 = X2b + (size_t)g * x2gs;
  const u16* W1t = W1tb + (size_t)g * wst;
  const u16* W2t = W2tb + (size_t)g * wst;
  const float* bias = biasb + (size_t)g * bst;
  u16* Y = Yb + (size_t)g * ygs;
  int tid = threadIdx.x;
  int wave = tid >> 6, lane = tid & 63;
  int l15 = lane & 15, l4 = lane >> 4;
  int m0 = blockIdx.x * 128;
  int wr = wave >> 2, wc = wave & 3;
  const f32x4 fz = {0.f, 0.f, 0.f, 0.f};
  f32x4 acc[4][4];
#pragma unroll
  for (int a = 0; a < 4; ++a)
#pragma unroll
    for (int b = 0; b < 4; ++b) acc[a][b] = fz;

  auto stage = [&](int t) {
    const u16* xs = (t < 8) ? X1 : X2;
    int xrs = (t < 8) ? x1rs : x2rs;
    const u16* wsrc = (t < 8) ? W1t : W2t;
    int kb = (t & 7) * 32;
    int half = t & 1;
    {
      int flat = wave * 1024 + lane * 16;
      int row = flat >> 6, colb = flat & 63;
      int scol = colb ^ (((row >> 1) & 3) << 4);  // inverse-swizzle the SOURCE
      int gr = m0 + row;
      if (gr > NN - 1) gr = NN - 1;
      gload_lds16(xs + (size_t)gr * xrs + kb + (scol >> 1), smem + half * 8192 + flat);
    }
#pragma unroll
    for (int q = 0; q < 2; ++q) {
      int flat = q * 8192 + wave * 1024 + lane * 16;
      int row = flat >> 6, colb = flat & 63;
      int scol = colb ^ (((row >> 1) & 3) << 4);
      gload_lds16(wsrc + row * 256 + kb + (scol >> 1), smem + 16384 + half * 16384 + flat);
    }
  };

  stage(0);
  for (int kt = 0; kt < 16; ++kt) {
    if (kt < 15) {
      stage(kt + 1);
      asm volatile("s_waitcnt vmcnt(3)" ::: "memory");
    } else {
      asm volatile("s_waitcnt vmcnt(0)" ::: "memory");
    }
    __builtin_amdgcn_sched_barrier(0);
    __builtin_amdgcn_s_barrier();
    __builtin_amdgcn_sched_barrier(0);
    const char* Ab = smem + (kt & 1) * 8192;
    const char* Bb = smem + 16384 + (kt & 1) * 16384;
    bf16x8 af[4], bfv[4];
#pragma unroll
    for (int mi = 0; mi < 4; ++mi) {
      int r = wr * 64 + mi * 16 + l15;
      af[mi] = *(const bf16x8*)(Ab + r * 64 + ((l4 * 16) ^ (((r >> 1) & 3) << 4)));
    }
#pragma unroll
    for (int nj = 0; nj < 4; ++nj) {
      int c = wc * 64 + nj * 16 + l15;
      bfv[nj] = *(const bf16x8*)(Bb + c * 64 + ((l4 * 16) ^ (((c >> 1) & 3) << 4)));
    }
#pragma unroll
    for (int mi = 0; mi < 4; ++mi)
#pragma unroll
      for (int nj = 0; nj < 4; ++nj)
        acc[mi][nj] =
            __builtin_amdgcn_mfma_f32_16x16x32_bf16(af[mi], bfv[nj], acc[mi][nj], 0, 0, 0);
    __builtin_amdgcn_sched_barrier(0);
    __builtin_amdgcn_s_barrier();
  }

  if (!do_out) {
    // epilogue: C/D map col=lane&15, row=(lane>>4)*4+reg  [m89-verified]
#pragma unroll
    for (int mi = 0; mi < 4; ++mi) {
      int rbase = m0 + wr * 64 + mi * 16 + l4 * 4;
#pragma unroll
      for (int nj = 0; nj < 4; ++nj) {
        int col = wc * 64 + nj * 16 + l15;
        float bv = bias[col];
#pragma unroll
        for (int r2 = 0; r2 < 4; ++r2) {
          int row = rbase + r2;
          if (row < NN) {
            float v = acc[mi][nj][r2] + bv;
            if (relu) v = fmaxf(v, 0.f);
            Y[(size_t)row * yrs + col] = f2bf(v);
          }
        }
      }
    }
  } else {
    // fused out-projection: he2 = relu(acc+bias); Y4self/nb = he2 @ {oWr,oWn}
    int eabs = e0_base + g;
    const float2* wr2p = (const float2*)(oWr + (size_t)eabs * 512);
    const float2* wn2p = (const float2*)(oWn + (size_t)eabs * 512);
    float bv[4]; float2 wa[4], wb[4];
#pragma unroll
    for (int nj = 0; nj < 4; ++nj) {
      int col = wc * 64 + nj * 16 + l15;
      bv[nj] = bias[col];
      wa[nj] = wr2p[col];
      wb[nj] = wn2p[col];
    }
    float* y4red = (float*)smem;  // [128][4 wc][4] = 8KB (post-barrier reuse)
#pragma unroll
    for (int mi = 0; mi < 4; ++mi) {
#pragma unroll
      for (int r2 = 0; r2 < 4; ++r2) {
        float p0 = 0.f, p1 = 0.f, p2 = 0.f, p3 = 0.f;
#pragma unroll
        for (int nj = 0; nj < 4; ++nj) {
          float v = fmaxf(acc[mi][nj][r2] + bv[nj], 0.f);
          p0 += v * wa[nj].x; p1 += v * wa[nj].y;
          p2 += v * wb[nj].x; p3 += v * wb[nj].y;
        }
#pragma unroll
        for (int off2 = 1; off2 < 16; off2 <<= 1) {
          p0 += __shfl_xor(p0, off2); p1 += __shfl_xor(p1, off2);
          p2 += __shfl_xor(p2, off2); p3 += __shfl_xor(p3, off2);
        }
        if (l15 == 0) {
          int lr = wr * 64 + mi * 16 + l4 * 4 + r2;
          float* q = y4red + (lr * 4 + wc) * 4;
          q[0] = p0; q[1] = p1; q[2] = p2; q[3] = p3;
        }
      }
    }
    __syncthreads();
    if (tid < 128) {
      int row = m0 + tid;
      if (row < NN) {
        float s0 = 0.f, s1 = 0.f, n0 = 0.f, n1 = 0.f;
#pragma unroll
        for (int w2 = 0; w2 < 4; ++w2) {
          const float* q = y4red + (tid * 4 + w2) * 4;
          s0 += q[0]; s1 += q[1]; n0 += q[2]; n1 += q[3];
        }
        Y4self[row * 16 + eabs * 2] = s0;
        Y4self[row * 16 + eabs * 2 + 1] = s1;
        Y4nb[row * 16 + eabs * 2] = n0;
        Y4nb[row * 16 + eabs * 2 + 1] = n1;
      }
    }
  }
}

// ---------------- single-pass combine over all 8 experts ---------------------
__global__ __launch_bounds__(256) void k_combine(
    const int* __restrict__ rowptr, const int* __restrict__ csrc,
    const float* __restrict__ Y4self, const float* __restrict__ Y4nb,
    const float* __restrict__ sparse, const float* __restrict__ ob,
    float* __restrict__ out) {
  int t = blockIdx.x * 256 + threadIdx.x;
  int d = t >> 3, e = t & 7;
  if (d >= NN) return;
  float s0 = Y4self[d * 16 + e * 2], s1 = Y4self[d * 16 + e * 2 + 1];
  float n0 = 0.f, n1 = 0.f;
  for (int i = rowptr[d]; i < rowptr[d + 1]; ++i) {
    int s = csrc[i];
    float2 v = *(const float2*)(Y4nb + s * 16 + e * 2);  // 8 e-lanes: 64B coalesced
    n0 += v.x;
    n1 += v.y;
  }
  float w = sparse[d * 8 + e];
  float t0 = w * (s0 + n0 + ob[e * 2]);
  float t1 = w * (s1 + n1 + ob[e * 2 + 1]);
  t0 += __shfl_xor(t0, 1); t1 += __shfl_xor(t1, 1);
  t0 += __shfl_xor(t0, 2); t1 += __shfl_xor(t1, 2);
  t0 += __shfl_xor(t0, 4); t1 += __shfl_xor(t1, 4);
  if (e == 0) {
    out[d * 2] = t0;
    out[d * 2 + 1] = t1;
  }
}

extern "C" void kernel_launch(void* const* d_in, const int* in_sizes, int n_in,
                              void* d_out, int out_size, void* d_ws, size_t ws_size,
                              hipStream_t stream) {
  const float* x = (const float*)d_in[0];
  const int* ei = (const int*)d_in[1];
  const int* batch = (const int*)d_in[2];
  const float* enc_W = (const float*)d_in[3];
  const float* enc_b = (const float*)d_in[4];
  const float* rW1 = (const float*)d_in[5];
  const float* rb1 = (const float*)d_in[6];
  const float* rW2 = (const float*)d_in[7];
  const float* rb2 = (const float*)d_in[8];
  const float* hid_Wr = (const float*)d_in[9];
  const float* hid_Wn = (const float*)d_in[10];
  const float* hid_b = (const float*)d_in[11];
  const float* out_Wr = (const float*)d_in[12];
  const float* out_Wn = (const float*)d_in[13];
  const float* out_b = (const float*)d_in[14];
  float* out = (float*)d_out;

  char* ws = (char*)d_ws;
  size_t off = 0;
  auto alloc = [&](size_t bytes) -> void* {
    void* p = ws + off;
    off = (off + bytes + 511) & ~(size_t)511;
    return p;
  };
  const size_t HBYTES = (size_t)NN * 256 * 2;      // 25.6 MB
  u16* hb = (u16*)alloc(HBYTES);
  u16* agg0 = (u16*)alloc(HBYTES);
  u16* WrT = (u16*)alloc((size_t)24 * 65536 * 2);  // 3.15 MB
  u16* WnT = (u16*)alloc((size_t)24 * 65536 * 2);
  // contiguous zero region: deg | cursor | outdeg
  int* deg = (int*)alloc((size_t)NN * 4);
  int* cursor = (int*)alloc((size_t)NN * 4);
  int* outdeg = (int*)alloc((size_t)NN * 4);
  size_t zero_bytes = (size_t)((char*)(outdeg + NN) - (char*)deg);
  int* rowptr = (int*)alloc((size_t)(NN + 1) * 4);
  int* csrc = (int*)alloc((size_t)EE * 4);  // 3.2 MB
  float* gf = (float*)alloc(GG * 2 * 4);
  float* sparse = (float*)alloc((size_t)NN * 8 * 4);   // 1.6 MB
  float* Y4self = (float*)alloc((size_t)NN * 16 * 4);  // 3.2 MB
  float* Y4nb = (float*)alloc((size_t)NN * 16 * 4);    // 3.2 MB

  // Expert group size: he+agg pair = 51.2 MB per expert. Cap at 4 (L3 comfort).
  size_t rem = (ws_size > off) ? ws_size - off : 0;
  size_t per = 2 * HBYTES + 2048;
  int grp = (rem >= 4 * per) ? 4 : (rem >= 2 * per) ? 2 : (rem >= per) ? 1 : 0;
  if (grp == 0) {
    k_sentinel<<<1, 2, 0, stream>>>(out);
    return;
  }
  u16* heb = (u16*)alloc((size_t)grp * HBYTES);   // interleaved [node][g][256]
  u16* aggb = (u16*)alloc((size_t)grp * HBYTES);  // interleaved [node][g][256]
  const int RS = grp * 256;                       // interleaved row stride (elems)

  hipMemsetAsync(deg, 0, zero_bytes, stream);

  k_transpose2<<<(24 * 65536 + 255) / 256, 256, 0, stream>>>(hid_Wr, hid_Wn, WrT, WnT);
  k_hist<<<(EE + 255) / 256, 256, 0, stream>>>(ei, deg, outdeg);
  k_graph_feats<<<GG, 256, 0, stream>>>(batch, outdeg, gf);
  k_scan<<<1, 1024, 0, stream>>>(deg, rowptr);
  k_fill<<<(EE + 255) / 256, 256, 0, stream>>>(ei, rowptr, cursor, csrc);
  k_router<<<NN / 8, 256, 0, stream>>>(x, enc_W, enc_b, batch, gf, rW1, rb1, rW2, rb2,
                                       sparse, hb);

  const int GX = (NN + 127) / 128;  // 391 gemm blocks per expert
  const size_t HS = (size_t)NN * 256;
  (void)HS;

  // shared layer-0 aggregation of h (identical input for every expert)
  k_spmm256<<<(NN + 3) / 4, 256, 0, stream>>>(rowptr, csrc, hb, agg0);
  for (int e0 = 0; e0 < 8; e0 += grp) {
    // layer 0 (batched over grp experts): plain-layout inputs -> interleaved Y
    k_gemm<<<dim3(GX, grp), 512, 0, stream>>>(
        hb, 0, 256, agg0, 0, 256, WrT + e0 * 65536, WnT + e0 * 65536, 65536,
        hid_b + e0 * 256, 256, heb, 256, RS, 1, nullptr, nullptr, 0, nullptr, nullptr, 0);
    // layer 1 (interleaved throughout)
    k_spmm_intl<<<NN, 256, 0, stream>>>(rowptr, csrc, heb, aggb, RS);
    k_gemm<<<dim3(GX, grp), 512, 0, stream>>>(
        heb, 256, RS, aggb, 256, RS, WrT + (8 + e0) * 65536, WnT + (8 + e0) * 65536, 65536,
        hid_b + (8 + e0) * 256, 256, heb, 256, RS, 1, nullptr, nullptr, 0, nullptr, nullptr, 0);
    // layer 2 + fused out-projection (he2 never materialized)
    k_spmm_intl<<<NN, 256, 0, stream>>>(rowptr, csrc, heb, aggb, RS);
    k_gemm<<<dim3(GX, grp), 512, 0, stream>>>(
        heb, 256, RS, aggb, 256, RS, WrT + (16 + e0) * 65536, WnT + (16 + e0) * 65536, 65536,
        hid_b + (16 + e0) * 256, 256, nullptr, 0, 256, 1, out_Wr, out_Wn, e0,
        Y4self, Y4nb, 1);
  }
  k_combine<<<(NN * 8 + 255) / 256, 256, 0, stream>>>(rowptr, csrc, Y4self, Y4nb, sparse,
                                                      out_b, out);
}